// Round 16
// baseline (58.784 us; speedup 1.0000x reference)
//
#include <hip/hip_runtime.h>
#include <math.h>

#define NB 16
#define PLEN 1024
#define QLEN 256
#define DIM 256
#define MASKV -10000000.0f

typedef __attribute__((ext_vector_type(8))) short short8;
typedef __attribute__((ext_vector_type(4))) float f32x4;

union u4x16 { unsigned short u[4]; int2 v; };
union u8x16 { unsigned short u[8]; int4 v; };
union u16x16 { unsigned short u[16]; int4 v[2]; };

__device__ inline unsigned short f2bf(float x) {
  unsigned int u = __float_as_uint(x);
  u += 0x7FFF + ((u >> 16) & 1);          // round-to-nearest-even
  return (unsigned short)(u >> 16);
}
__device__ inline float bf2f(unsigned short u) {
  return __uint_as_float(((unsigned int)u) << 16);
}
__device__ inline int4 pack8(float4 a, float4 b) {
  u8x16 o;
  o.u[0] = f2bf(a.x); o.u[1] = f2bf(a.y); o.u[2] = f2bf(a.z); o.u[3] = f2bf(a.w);
  o.u[4] = f2bf(b.x); o.u[5] = f2bf(b.y); o.u[6] = f2bf(b.z); o.u[7] = f2bf(b.w);
  return o.v;
}

// ---------------- k_scoreA (grid NB*16, 1024 thr = 16 waves): 64 p-rows x 256 q.
// Inline passage+question prep + score GEMM + mask + col partials + exact row softmax
// -> P2Q, P2Qt, RS (= RL*exp(RM)), PbT.  tile<4 blocks also emit QbT.
__global__ __launch_bounds__(1024) void k_scoreA(
    const float* __restrict__ passage, const float* __restrict__ question,
    const float* __restrict__ Wg,
    const int* __restrict__ pmask, const int* __restrict__ qmask,
    const float* __restrict__ bias,
    unsigned short* __restrict__ PbT, unsigned short* __restrict__ QbT,
    float* __restrict__ CM, float* __restrict__ CL,
    float* __restrict__ RS,
    unsigned short* __restrict__ P2Q, unsigned short* __restrict__ P2Qt) {
  int bid0 = blockIdx.x;
  int bid = (bid0 & 7) * 32 + (bid0 >> 3);           // XCD swizzle (256 = 8 * 32, bijective)
  int b = bid >> 4;
  int tile = bid & 15;
  int p0 = tile * 64;
  int t = threadIdx.x, lane = t & 63, wv = t >> 6;   // 16 waves
  int s = wv >> 2, h = wv & 3;
  __shared__ __align__(16) unsigned short As[2][64][40];
  __shared__ __align__(16) unsigned short Bs[2][256][40];
  __shared__ __align__(16) unsigned short Pl[64][264];
  __shared__ float redM[4][256], redL[4][256];
  __shared__ float rowM[64][4], rowL[64][4];
  __shared__ float spS[64];
  __shared__ float sqS[256];

  int rb = t >> 2, cb = (t & 3) * 8;     // Bs staging: row, col-chunk (8)
  int pr = t >> 4, pc = (t & 15) * 2;    // passage fp32 load: row, col-pair
  const float* psrc = passage + ((size_t)b * PLEN + p0 + pr) * DIM;
  const float* qsrc = question + ((size_t)b * QLEN + rb) * DIM;
  const float* wq = Wg + DIM;

  // ---- phase 1: inline-prep + score GEMM (64 x 256, K = 256), dbuf
  f32x4 acc[4] = {};
  float spp = 0.f, sqq = 0.f;
  float4 qa = *(const float4*)&qsrc[cb];
  float4 qb_ = *(const float4*)&qsrc[cb + 4];
  float2 xv = *(const float2*)(psrc + pc);
  {
    sqq += qa.x * wq[cb]     + qa.y * wq[cb + 1] + qa.z * wq[cb + 2] + qa.w * wq[cb + 3]
         + qb_.x * wq[cb + 4] + qb_.y * wq[cb + 5] + qb_.z * wq[cb + 6] + qb_.w * wq[cb + 7];
    *(int4*)&Bs[0][rb][cb] = pack8(qa, qb_);
    spp += xv.x * Wg[pc] + xv.y * Wg[pc + 1];
    unsigned int raw = (unsigned int)f2bf(xv.x) | (((unsigned int)f2bf(xv.y)) << 16);
    unsigned int wgt = (unsigned int)f2bf(xv.x * Wg[2 * DIM + pc])
                     | (((unsigned int)f2bf(xv.y * Wg[2 * DIM + pc + 1])) << 16);
    *(unsigned int*)&Pl[pr][pc] = raw;
    *(unsigned int*)&As[0][pr][pc] = wgt;
  }
  __syncthreads();
  int cur = 0;
  for (int ki = 0; ki < 8; ++ki) {
    float2 xn; float4 qa2, qb2;
    if (ki < 7) {
      int kt = (ki + 1) * 32;
      qa2 = *(const float4*)&qsrc[kt + cb];
      qb2 = *(const float4*)&qsrc[kt + cb + 4];
      xn = *(const float2*)(psrc + kt + pc);
    }
    short8 af = *(const short8*)&As[cur][s * 16 + (lane & 15)][(lane >> 4) * 8];
    for (int j = 0; j < 4; ++j) {
      short8 bf = *(const short8*)&Bs[cur][h * 64 + j * 16 + (lane & 15)][(lane >> 4) * 8];
      acc[j] = __builtin_amdgcn_mfma_f32_16x16x32_bf16(af, bf, acc[j], 0, 0, 0);
    }
    if (ki < 7) {
      int kt = (ki + 1) * 32;
      int dq = kt + cb, dp = kt + pc;
      sqq += qa2.x * wq[dq]     + qa2.y * wq[dq + 1] + qa2.z * wq[dq + 2] + qa2.w * wq[dq + 3]
           + qb2.x * wq[dq + 4] + qb2.y * wq[dq + 5] + qb2.z * wq[dq + 6] + qb2.w * wq[dq + 7];
      spp += xn.x * Wg[dp] + xn.y * Wg[dp + 1];
      unsigned int raw = (unsigned int)f2bf(xn.x) | (((unsigned int)f2bf(xn.y)) << 16);
      unsigned int wgt = (unsigned int)f2bf(xn.x * Wg[2 * DIM + dp])
                       | (((unsigned int)f2bf(xn.y * Wg[2 * DIM + dp + 1])) << 16);
      int nxt = cur ^ 1;
      *(unsigned int*)&Pl[pr][dp] = raw;
      *(unsigned int*)&As[nxt][pr][pc] = wgt;
      *(int4*)&Bs[nxt][rb][cb] = pack8(qa2, qb2);
      cur = nxt;
    }
    __syncthreads();
  }

  // ---- sq reduce -> sqS ; sp reduce -> spS ; PbT transpose-out
  sqq += __shfl_xor(sqq, 1, 64);
  sqq += __shfl_xor(sqq, 2, 64);
  if ((t & 3) == 0) sqS[rb] = sqq;
  spp += __shfl_xor(spp, 1, 64);
  spp += __shfl_xor(spp, 2, 64);
  spp += __shfl_xor(spp, 4, 64);
  spp += __shfl_xor(spp, 8, 64);
  if ((t & 15) == 0) spS[pr] = spp;
  {
    int d = t >> 2, ch = t & 3;
    u16x16 o;
    for (int e = 0; e < 16; ++e) o.u[e] = Pl[ch * 16 + e][d];
    unsigned short* dst = PbT + ((size_t)b * DIM + d) * PLEN + p0 + ch * 16;
    *(int4*)dst = o.v[0];
    *(int4*)(dst + 8) = o.v[1];
  }
  __syncthreads();

  // ---- phase 2: bias + mask epilogue
  float b0 = bias[0];
  int prow[4]; float spv[4]; int pmv[4];
  for (int r = 0; r < 4; ++r) {
    int rl = s * 16 + (lane >> 4) * 4 + r;
    prow[r] = p0 + rl;
    spv[r] = spS[rl] + b0;
    pmv[r] = pmask[b * PLEN + prow[r]];
  }
  float sqv[4]; int qmv[4];
  for (int j = 0; j < 4; ++j) {
    int q = h * 64 + j * 16 + (lane & 15);
    sqv[j] = sqS[q];
    qmv[j] = qmask[b * QLEN + q];
  }
  for (int j = 0; j < 4; ++j)
    for (int r = 0; r < 4; ++r) {
      float v = acc[j][r] + spv[r] + sqv[j];
      if (pmv[r] | qmv[j]) v = MASKV;
      acc[j][r] = v;
    }

  // ---- phase 3a: column + row partials
  for (int j = 0; j < 4; ++j) {
    float m = fmaxf(fmaxf(acc[j][0], acc[j][1]), fmaxf(acc[j][2], acc[j][3]));
    m = fmaxf(m, __shfl_xor(m, 16, 64));
    m = fmaxf(m, __shfl_xor(m, 32, 64));
    float e = 0.f;
    for (int r = 0; r < 4; ++r) e += __expf(acc[j][r] - m);
    e += __shfl_xor(e, 16, 64);
    e += __shfl_xor(e, 32, 64);
    if ((lane >> 4) == 0) {
      redM[s][h * 64 + j * 16 + (lane & 15)] = m;
      redL[s][h * 64 + j * 16 + (lane & 15)] = e;
    }
  }
  for (int r = 0; r < 4; ++r) {
    int rl = s * 16 + (lane >> 4) * 4 + r;
    float m = acc[0][r];
    for (int j = 1; j < 4; ++j) m = fmaxf(m, acc[j][r]);
    for (int msk = 1; msk <= 8; msk <<= 1) m = fmaxf(m, __shfl_xor(m, msk, 64));
    float l = 0.f;
    for (int j = 0; j < 4; ++j) l += __expf(acc[j][r] - m);
    for (int msk = 1; msk <= 8; msk <<= 1) l += __shfl_xor(l, msk, 64);
    if ((lane & 15) == 0) { rowM[rl][h] = m; rowL[rl][h] = l; }
  }
  __syncthreads();

  // ---- phase 3b: CM/CL store
  if (t < 256) {
    int q = t;
    float M = fmaxf(fmaxf(redM[0][q], redM[1][q]), fmaxf(redM[2][q], redM[3][q]));
    float L = redL[0][q] * __expf(redM[0][q] - M) + redL[1][q] * __expf(redM[1][q] - M)
            + redL[2][q] * __expf(redM[2][q] - M) + redL[3][q] * __expf(redM[3][q] - M);
    size_t o = ((size_t)b * 16 + tile) * QLEN + q;
    CM[o] = M; CL[o] = L;
  }

  // ---- phase 4: exact row softmax -> Pl (bf16) + RS = l*exp(m)
  for (int r = 0; r < 4; ++r) {
    int rl = s * 16 + (lane >> 4) * 4 + r;
    float m0 = rowM[rl][0], m1 = rowM[rl][1], m2 = rowM[rl][2], m3 = rowM[rl][3];
    float m = fmaxf(fmaxf(m0, m1), fmaxf(m2, m3));
    float l = rowL[rl][0] * __expf(m0 - m) + rowL[rl][1] * __expf(m1 - m)
            + rowL[rl][2] * __expf(m2 - m) + rowL[rl][3] * __expf(m3 - m);
    if (h == 0 && (lane & 15) == 0)
      RS[(size_t)b * PLEN + p0 + rl] = l * __expf(m);   // 0 for masked rows (m = MASKV)
    float inv = 1.0f / l;
    for (int j = 0; j < 4; ++j) {
      float e = (pmv[r] | qmv[j]) ? 0.0f : __expf(acc[j][r] - m) * inv;
      Pl[rl][h * 64 + j * 16 + (lane & 15)] = f2bf(e);
    }
  }
  __syncthreads();

  // ---- P2Q row-major store
  for (int k = 0; k < 2; ++k) {
    int idx = t + k * 1024;
    int row = idx >> 5, c8 = idx & 31;
    *(int4*)&P2Q[((size_t)b * PLEN + p0 + row) * QLEN + c8 * 8] = *(const int4*)&Pl[row][c8 * 8];
  }
  // ---- P2Qt transposed store
  {
    int q = t >> 2, pcc = t & 3;
    u16x16 o;
    for (int e = 0; e < 16; ++e) o.u[e] = Pl[pcc * 16 + e][q];
    unsigned short* dst = P2Qt + ((size_t)b * QLEN + q) * PLEN + p0 + pcc * 16;
    *(int4*)dst = o.v[0];
    *(int4*)(dst + 8) = o.v[1];
  }

  // ---- QbT production (tile 0..3 only)
  if (tile < 4) {
    __syncthreads();
    int r0 = tile * 64;
    const float* src = question + ((size_t)b * QLEN + r0) * DIM;
    int row = t >> 4, c0 = (t & 15) * 16;
    for (int i = 0; i < 4; ++i) {
      int d = c0 + i * 4;
      float4 x = *(const float4*)&src[(size_t)row * DIM + d];
      u4x16 tv;
      tv.u[0] = f2bf(x.x); tv.u[1] = f2bf(x.y); tv.u[2] = f2bf(x.z); tv.u[3] = f2bf(x.w);
      *(int2*)&Pl[row][d] = tv.v;
    }
    __syncthreads();
    for (int it = 0; it < 2; ++it) {
      int g = t + it * 1024;
      int d = g >> 3, ch = g & 7;
      u8x16 o;
      for (int e = 0; e < 8; ++e) o.u[e] = Pl[ch * 8 + e][d];
      *(int4*)&QbT[(size_t)(b * DIM + d) * QLEN + r0 + ch * 8] = o.v;
    }
  }
}

// ---------------- k_mid (512 thr, grid NB*32): heterogeneous overlap.
// Blocks [0, NB*16): fused col-softmax + qatt GEMM -> QATTt  (factored scales, dbuf, no exp)
// Blocks [NB*16, NB*32): out1 = P2Q @ QbT^T (128p x 128d tiles).
__global__ __launch_bounds__(512) void k_mid(
    const unsigned short* __restrict__ P2Qt, const unsigned short* __restrict__ PbT,
    const unsigned short* __restrict__ P2Q, const unsigned short* __restrict__ QbT,
    const float* __restrict__ RS,
    const float* __restrict__ CM, const float* __restrict__ CL,
    unsigned short* __restrict__ QATTt, float* __restrict__ out1) {
  __shared__ __align__(16) char smem[40960];
  int t = threadIdx.x, lane = t & 63, wid = t >> 6;

  if (blockIdx.x < NB * 16) {
    // ======== qatt2: W2[p,q] = P2Q[p,q] * RS[p] * CS[q] ========
    int bid = blockIdx.x;
    int b = bid >> 4, dt = (bid >> 2) & 3, qt = bid & 3;
    int wm = wid >> 2, wn = wid & 3;                 // wave = 32 d x 16 q
    typedef unsigned short row72[72];
    row72* Wt = (row72*)smem;                        // [2][64][72]: 18432 B
    row72* At = (row72*)(smem + 18432);              // [2][64][72]: 18432 B
    float* CSs = (float*)(smem + 36864);             // 256 B
    if (t < 64) {
      int q = qt * 64 + t;
      float M = CM[((size_t)b * 16) * QLEN + q];
      for (int tm = 1; tm < 16; ++tm)
        M = fmaxf(M, CM[((size_t)b * 16 + tm) * QLEN + q]);
      float L = 0.f;
      for (int tm = 0; tm < 16; ++tm) {
        size_t o = ((size_t)b * 16 + tm) * QLEN + q;
        L += CL[o] * __expf(CM[o] - M);
      }
      CSs[t] = (M < -1.0e6f) ? 0.0f : __expf(-M) / L;   // masked column -> 0
    }

    int rrow = t >> 3;            // q-row for Wt, d-row for At
    int pch = (t & 7) * 8;        // p-chunk within 64-p slice
    const unsigned short* Wsrc = P2Qt + ((size_t)b * QLEN + qt * 64 + rrow) * PLEN + pch;
    const unsigned short* Asrc = PbT + ((size_t)b * DIM + dt * 64 + rrow) * PLEN + pch;
    const float* rsB = RS + (size_t)b * PLEN + pch;

    f32x4 acc[2] = {};
    int4 wvv = *(const int4*)Wsrc;
    int4 av = *(const int4*)Asrc;
    float4 rs0 = *(const float4*)rsB, rs1 = *(const float4*)(rsB + 4);
    __syncthreads();             // CSs ready
    float cs = CSs[rrow];

    // prologue: stage buffer 0
    {
      float rsv[8] = {rs0.x, rs0.y, rs0.z, rs0.w, rs1.x, rs1.y, rs1.z, rs1.w};
      const unsigned short* wu = (const unsigned short*)&wvv;
      u8x16 wo;
#pragma unroll
      for (int e = 0; e < 8; ++e) wo.u[e] = f2bf(bf2f(wu[e]) * rsv[e] * cs);
      *(int4*)&Wt[rrow][pch] = wo.v;
      *(int4*)&At[rrow][pch] = av;
    }
    __syncthreads();
    int cur = 0;
    for (int ps = 0; ps < 16; ++ps) {
      if (ps < 15) {
        int off = (ps + 1) * 64;
        wvv = *(const int4*)(Wsrc + off);
        av = *(const int4*)(Asrc + off);
        rs0 = *(const float4*)(rsB + off); rs1 = *(const float4*)(rsB + off + 4);
      }
      for (int kk = 0; kk < 64; kk += 32) {
        short8 bf = *(const short8*)&Wt[cur * 64 + wn * 16 + (lane & 15)][kk + (lane >> 4) * 8];
        for (int i = 0; i < 2; ++i) {
          short8 af = *(const short8*)&At[cur * 64 + wm * 32 + i * 16 + (lane & 15)][kk + (lane >> 4) * 8];
          acc[i] = __builtin_amdgcn_mfma_f32_16x16x32_bf16(af, bf, acc[i], 0, 0, 0);
        }
      }
      if (ps < 15) {
        float rsv[8] = {rs0.x, rs0.y, rs0.z, rs0.w, rs1.x, rs1.y, rs1.z, rs1.w};
        const unsigned short* wu = (const unsigned short*)&wvv;
        u8x16 wo;
#pragma unroll
        for (int e = 0; e < 8; ++e) wo.u[e] = f2bf(bf2f(wu[e]) * rsv[e] * cs);
        int nxt = cur ^ 1;
        *(int4*)&Wt[nxt * 64 + rrow][pch] = wo.v;
        *(int4*)&At[nxt * 64 + rrow][pch] = av;
        cur = nxt;
      }
      __syncthreads();
    }
    int d0 = dt * 64 + wm * 32, q0 = qt * 64 + wn * 16;
    for (int i = 0; i < 2; ++i)
      for (int rr = 0; rr < 4; ++rr) {
        int d = d0 + i * 16 + (lane >> 4) * 4 + rr;
        QATTt[((size_t)b * DIM + d) * QLEN + q0 + (lane & 15)] = f2bf(acc[i][rr]);
      }
  } else {
    // ======== out1 = P2Q @ QbT^T ========
    int bid = blockIdx.x - NB * 16;
    int b = bid >> 4;
    int tm = (bid >> 1) & 7;
    int tn = bid & 1;
    const unsigned short* A  = P2Q + ((size_t)b * PLEN + tm * 128) * QLEN;
    const unsigned short* B1 = QbT + ((size_t)b * DIM + tn * 128) * QLEN;
    typedef unsigned short row40[40];
    row40* As2 = (row40*)smem;
    row40* Bq = (row40*)(smem + 20480);
    int wm = wid >> 2, wn = wid & 3;           // wave = 64 p x 32 d
    f32x4 acc1[4][2] = {};
    int r = t >> 2, c = (t & 3) * 8;
    int4 rav = *(const int4*)&A[(size_t)r * QLEN + c];
    int4 rb1 = *(const int4*)&B1[(size_t)r * QLEN + c];
    *(int4*)&As2[r][c] = rav;
    *(int4*)&Bq[r][c] = rb1;
    __syncthreads();
    int cur = 0;
    for (int ki = 0; ki < 8; ++ki) {
      if (ki < 7) {
        int kt = (ki + 1) * 32;
        rav = *(const int4*)&A[(size_t)r * QLEN + kt + c];
        rb1 = *(const int4*)&B1[(size_t)r * QLEN + kt + c];
      }
      short8 af[4], b1v[2];
      for (int i = 0; i < 4; ++i)
        af[i] = *(const short8*)&As2[cur * 128 + wm * 64 + i * 16 + (lane & 15)][(lane >> 4) * 8];
      for (int j = 0; j < 2; ++j)
        b1v[j] = *(const short8*)&Bq[cur * 128 + wn * 32 + j * 16 + (lane & 15)][(lane >> 4) * 8];
      for (int i = 0; i < 4; ++i)
        for (int j = 0; j < 2; ++j)
          acc1[i][j] = __builtin_amdgcn_mfma_f32_16x16x32_bf16(af[i], b1v[j], acc1[i][j], 0, 0, 0);
      if (ki < 7) {
        int nxt = cur ^ 1;
        *(int4*)&As2[nxt * 128 + r][c] = rav;
        *(int4*)&Bq[nxt * 128 + r][c] = rb1;
        cur = nxt;
      }
      __syncthreads();
    }
    int p0 = tm * 128 + wm * 64, d0 = tn * 128 + wn * 32;
    for (int i = 0; i < 4; ++i)
      for (int rr = 0; rr < 4; ++rr) {
        int p = p0 + i * 16 + (lane >> 4) * 4 + rr;
        size_t rowo = ((size_t)b * PLEN + p) * DIM;
        for (int j = 0; j < 2; ++j) {
          int d = d0 + j * 16 + (lane & 15);
          out1[rowo + d] = acc1[i][j][rr];
        }
      }
  }
}

// ---------------- k_final2 (512 thr): out2 = P2Q @ QATTt^T; 128p x 128d, dbuf
__global__ __launch_bounds__(512) void k_final2(
    const unsigned short* __restrict__ P2Q, const unsigned short* __restrict__ QATTt,
    float* __restrict__ out2) {
  int bid = blockIdx.x;
  int b = bid >> 4;
  int tm = (bid >> 1) & 7;
  int tn = bid & 1;
  const unsigned short* A  = P2Q + ((size_t)b * PLEN + tm * 128) * QLEN;
  const unsigned short* B2 = QATTt + ((size_t)b * DIM + tn * 128) * QLEN;
  __shared__ __align__(16) unsigned short As[2][128][40];
  __shared__ __align__(16) unsigned short Bc[2][128][40];
  int t = threadIdx.x, lane = t & 63, wid = t >> 6;
  int wm = wid >> 2, wn = wid & 3;       // wave = 64 p x 32 d
  f32x4 acc[4][2] = {};
  int r = t >> 2, c = (t & 3) * 8;
  int4 rav = *(const int4*)&A[(size_t)r * QLEN + c];
  int4 rb2 = *(const int4*)&B2[(size_t)r * QLEN + c];
  *(int4*)&As[0][r][c] = rav;
  *(int4*)&Bc[0][r][c] = rb2;
  __syncthreads();
  int cur = 0;
  for (int ki = 0; ki < 8; ++ki) {
    if (ki < 7) {
      int kt = (ki + 1) * 32;
      rav = *(const int4*)&A[(size_t)r * QLEN + kt + c];
      rb2 = *(const int4*)&B2[(size_t)r * QLEN + kt + c];
    }
    short8 af[4], bc[2];
    for (int i = 0; i < 4; ++i)
      af[i] = *(const short8*)&As[cur][wm * 64 + i * 16 + (lane & 15)][(lane >> 4) * 8];
    for (int j = 0; j < 2; ++j)
      bc[j] = *(const short8*)&Bc[cur][wn * 32 + j * 16 + (lane & 15)][(lane >> 4) * 8];
    for (int i = 0; i < 4; ++i)
      for (int j = 0; j < 2; ++j)
        acc[i][j] = __builtin_amdgcn_mfma_f32_16x16x32_bf16(af[i], bc[j], acc[i][j], 0, 0, 0);
    if (ki < 7) {
      int nxt = cur ^ 1;
      *(int4*)&As[nxt][r][c] = rav;
      *(int4*)&Bc[nxt][r][c] = rb2;
      cur = nxt;
    }
    __syncthreads();
  }
  int p0 = tm * 128 + wm * 64, d0 = tn * 128 + wn * 32;
  for (int i = 0; i < 4; ++i)
    for (int rr = 0; rr < 4; ++rr) {
      int p = p0 + i * 16 + (lane >> 4) * 4 + rr;
      size_t rowo = ((size_t)b * PLEN + p) * DIM;
      for (int j = 0; j < 2; ++j) {
        int d = d0 + j * 16 + (lane & 15);
        out2[rowo + d] = acc[i][j][rr];
      }
    }
}

extern "C" void kernel_launch(void* const* d_in, const int* in_sizes, int n_in,
                              void* d_out, int out_size, void* d_ws, size_t ws_size,
                              hipStream_t stream) {
  const float* passage  = (const float*)d_in[0];
  const float* question = (const float*)d_in[1];
  const int*   pmask    = (const int*)d_in[2];
  const int*   qmask    = (const int*)d_in[3];
  const float* W        = (const float*)d_in[4];
  const float* bias     = (const float*)d_in[5];
  float* out = (float*)d_out;

  const size_t NS = (size_t)NB * PLEN * QLEN;    // 4,194,304
  const size_t NQ = (size_t)NB * QLEN * DIM;     // 1,048,576
  char* w = (char*)d_ws;
  unsigned short* PbT  = (unsigned short*)w; w += NS * 2;
  unsigned short* QbT  = (unsigned short*)w; w += NQ * 2;
  unsigned short* P2Q  = (unsigned short*)w; w += NS * 2;
  unsigned short* P2Qt = (unsigned short*)w; w += NS * 2;
  unsigned short* QATTt = (unsigned short*)w; w += NQ * 2;
  float* CM = (float*)w;                     w += (size_t)NB * 16 * QLEN * 4;
  float* CL = (float*)w;                     w += (size_t)NB * 16 * QLEN * 4;
  float* RS = (float*)w;

  float* out1 = out;
  float* out2 = out + (size_t)NB * PLEN * DIM;

  k_scoreA<<<dim3(NB * 16), dim3(1024), 0, stream>>>(
      passage, question, W, pmask, qmask, bias, PbT, QbT, CM, CL, RS, P2Q, P2Qt);
  k_mid<<<dim3(NB * 32), dim3(512), 0, stream>>>(
      P2Qt, PbT, P2Q, QbT, RS, CM, CL, QATTt, out1);
  k_final2<<<dim3(NB * 16), dim3(512), 0, stream>>>(
      P2Q, QATTt, out2);
}

// Round 17
// 53.578 us; speedup vs baseline: 1.0972x; 1.0972x over previous
//
#include <hip/hip_runtime.h>
#include <math.h>

#define NB 16
#define PLEN 1024
#define QLEN 256
#define DIM 256
#define MASKV -10000000.0f

typedef __attribute__((ext_vector_type(8))) short short8;
typedef __attribute__((ext_vector_type(4))) float f32x4;

union u4x16 { unsigned short u[4]; int2 v; };
union u8x16 { unsigned short u[8]; int4 v; };
union u16x16 { unsigned short u[16]; int4 v[2]; };

__device__ inline unsigned short f2bf(float x) {
  unsigned int u = __float_as_uint(x);
  u += 0x7FFF + ((u >> 16) & 1);          // round-to-nearest-even
  return (unsigned short)(u >> 16);
}
__device__ inline float bf2f(unsigned short u) {
  return __uint_as_float(((unsigned int)u) << 16);
}
__device__ inline int4 pack8(float4 a, float4 b) {
  u8x16 o;
  o.u[0] = f2bf(a.x); o.u[1] = f2bf(a.y); o.u[2] = f2bf(a.z); o.u[3] = f2bf(a.w);
  o.u[4] = f2bf(b.x); o.u[5] = f2bf(b.y); o.u[6] = f2bf(b.z); o.u[7] = f2bf(b.w);
  return o.v;
}

// ---------------- k_scoreA (grid NB*16, 1024 thr = 16 waves): 64 p-rows x 256 q.
// Inline prep + score GEMM + mask + UNNORMALIZED-exp softmax sums:
//   RS[p] = sum_q exp(S), CL[tile][q] = partial sum_p exp(S), P2Q = exp(S)/RS.
__global__ __launch_bounds__(1024) void k_scoreA(
    const float* __restrict__ passage, const float* __restrict__ question,
    const float* __restrict__ Wg,
    const int* __restrict__ pmask, const int* __restrict__ qmask,
    const float* __restrict__ bias,
    unsigned short* __restrict__ PbT, unsigned short* __restrict__ QbT,
    float* __restrict__ CL, float* __restrict__ RS,
    unsigned short* __restrict__ P2Q, unsigned short* __restrict__ P2Qt) {
  int bid0 = blockIdx.x;
  int bid = (bid0 & 7) * 32 + (bid0 >> 3);           // XCD swizzle (256 = 8 * 32, bijective)
  int b = bid >> 4;
  int tile = bid & 15;
  int p0 = tile * 64;
  int t = threadIdx.x, lane = t & 63, wv = t >> 6;   // 16 waves
  int s = wv >> 2, h = wv & 3;
  __shared__ __align__(16) unsigned short As[2][64][40];
  __shared__ __align__(16) unsigned short Bs[2][256][40];
  __shared__ __align__(16) unsigned short Pl[64][264];
  __shared__ float redL[4][256];
  __shared__ float rowL[64][4];
  __shared__ float spS[64];
  __shared__ float sqS[256];

  int rb = t >> 2, cb = (t & 3) * 8;     // Bs staging: row, col-chunk (8)
  int pr = t >> 4, pc = (t & 15) * 2;    // passage fp32 load: row, col-pair
  const float* psrc = passage + ((size_t)b * PLEN + p0 + pr) * DIM;
  const float* qsrc = question + ((size_t)b * QLEN + rb) * DIM;
  const float* wq = Wg + DIM;

  // ---- phase 1: inline-prep + score GEMM (64 x 256, K = 256), dbuf
  f32x4 acc[4] = {};
  float spp = 0.f, sqq = 0.f;
  float4 qa = *(const float4*)&qsrc[cb];
  float4 qb_ = *(const float4*)&qsrc[cb + 4];
  float2 xv = *(const float2*)(psrc + pc);
  {
    sqq += qa.x * wq[cb]     + qa.y * wq[cb + 1] + qa.z * wq[cb + 2] + qa.w * wq[cb + 3]
         + qb_.x * wq[cb + 4] + qb_.y * wq[cb + 5] + qb_.z * wq[cb + 6] + qb_.w * wq[cb + 7];
    *(int4*)&Bs[0][rb][cb] = pack8(qa, qb_);
    spp += xv.x * Wg[pc] + xv.y * Wg[pc + 1];
    unsigned int raw = (unsigned int)f2bf(xv.x) | (((unsigned int)f2bf(xv.y)) << 16);
    unsigned int wgt = (unsigned int)f2bf(xv.x * Wg[2 * DIM + pc])
                     | (((unsigned int)f2bf(xv.y * Wg[2 * DIM + pc + 1])) << 16);
    *(unsigned int*)&Pl[pr][pc] = raw;
    *(unsigned int*)&As[0][pr][pc] = wgt;
  }
  __syncthreads();
  int cur = 0;
  for (int ki = 0; ki < 8; ++ki) {
    float2 xn; float4 qa2, qb2;
    if (ki < 7) {
      int kt = (ki + 1) * 32;
      qa2 = *(const float4*)&qsrc[kt + cb];
      qb2 = *(const float4*)&qsrc[kt + cb + 4];
      xn = *(const float2*)(psrc + kt + pc);
    }
    short8 af = *(const short8*)&As[cur][s * 16 + (lane & 15)][(lane >> 4) * 8];
    for (int j = 0; j < 4; ++j) {
      short8 bf = *(const short8*)&Bs[cur][h * 64 + j * 16 + (lane & 15)][(lane >> 4) * 8];
      acc[j] = __builtin_amdgcn_mfma_f32_16x16x32_bf16(af, bf, acc[j], 0, 0, 0);
    }
    if (ki < 7) {
      int kt = (ki + 1) * 32;
      int dq = kt + cb, dp = kt + pc;
      sqq += qa2.x * wq[dq]     + qa2.y * wq[dq + 1] + qa2.z * wq[dq + 2] + qa2.w * wq[dq + 3]
           + qb2.x * wq[dq + 4] + qb2.y * wq[dq + 5] + qb2.z * wq[dq + 6] + qb2.w * wq[dq + 7];
      spp += xn.x * Wg[dp] + xn.y * Wg[dp + 1];
      unsigned int raw = (unsigned int)f2bf(xn.x) | (((unsigned int)f2bf(xn.y)) << 16);
      unsigned int wgt = (unsigned int)f2bf(xn.x * Wg[2 * DIM + dp])
                       | (((unsigned int)f2bf(xn.y * Wg[2 * DIM + dp + 1])) << 16);
      int nxt = cur ^ 1;
      *(unsigned int*)&Pl[pr][dp] = raw;
      *(unsigned int*)&As[nxt][pr][pc] = wgt;
      *(int4*)&Bs[nxt][rb][cb] = pack8(qa2, qb2);
      cur = nxt;
    }
    __syncthreads();
  }

  // ---- sq reduce -> sqS ; sp reduce -> spS ; PbT transpose-out
  sqq += __shfl_xor(sqq, 1, 64);
  sqq += __shfl_xor(sqq, 2, 64);
  if ((t & 3) == 0) sqS[rb] = sqq;
  spp += __shfl_xor(spp, 1, 64);
  spp += __shfl_xor(spp, 2, 64);
  spp += __shfl_xor(spp, 4, 64);
  spp += __shfl_xor(spp, 8, 64);
  if ((t & 15) == 0) spS[pr] = spp;
  {
    int d = t >> 2, ch = t & 3;
    u16x16 o;
    for (int e = 0; e < 16; ++e) o.u[e] = Pl[ch * 16 + e][d];
    unsigned short* dst = PbT + ((size_t)b * DIM + d) * PLEN + p0 + ch * 16;
    *(int4*)dst = o.v[0];
    *(int4*)(dst + 8) = o.v[1];
  }
  __syncthreads();

  // ---- phase 2: bias + mask epilogue, then convert to exp-space
  float b0 = bias[0];
  float spv[4]; int pmv[4];
  for (int r = 0; r < 4; ++r) {
    int rl = s * 16 + (lane >> 4) * 4 + r;
    spv[r] = spS[rl] + b0;
    pmv[r] = pmask[b * PLEN + p0 + rl];
  }
  float sqv[4]; int qmv[4];
  for (int j = 0; j < 4; ++j) {
    int q = h * 64 + j * 16 + (lane & 15);
    sqv[j] = sqS[q];
    qmv[j] = qmask[b * QLEN + q];
  }
  for (int j = 0; j < 4; ++j)
    for (int r = 0; r < 4; ++r) {
      float v = acc[j][r] + spv[r] + sqv[j];
      acc[j][r] = (pmv[r] | qmv[j]) ? 0.0f : __expf(v);   // exp(MASKV) == 0
    }

  // ---- phase 3a: column partial sums (per strip) + row partial sums (per quarter)
  for (int j = 0; j < 4; ++j) {
    float e = acc[j][0] + acc[j][1] + acc[j][2] + acc[j][3];
    e += __shfl_xor(e, 16, 64);
    e += __shfl_xor(e, 32, 64);
    if ((lane >> 4) == 0)
      redL[s][h * 64 + j * 16 + (lane & 15)] = e;
  }
  for (int r = 0; r < 4; ++r) {
    int rl = s * 16 + (lane >> 4) * 4 + r;
    float l = acc[0][r] + acc[1][r] + acc[2][r] + acc[3][r];
    for (int msk = 1; msk <= 8; msk <<= 1) l += __shfl_xor(l, msk, 64);
    if ((lane & 15) == 0) rowL[rl][h] = l;
  }
  __syncthreads();

  // ---- phase 3b: CL (column partial sums for this tile)
  if (t < 256) {
    int q = t;
    CL[((size_t)b * 16 + tile) * QLEN + q] = redL[0][q] + redL[1][q] + redL[2][q] + redL[3][q];
  }

  // ---- phase 4: P2Q = exp/RS ; store RS
  for (int r = 0; r < 4; ++r) {
    int rl = s * 16 + (lane >> 4) * 4 + r;
    float l = rowL[rl][0] + rowL[rl][1] + rowL[rl][2] + rowL[rl][3];
    if (h == 0 && (lane & 15) == 0)
      RS[(size_t)b * PLEN + p0 + rl] = l;
    float inv = (l > 0.f) ? 1.0f / l : 0.0f;        // fully-masked row -> 0
    for (int j = 0; j < 4; ++j)
      Pl[rl][h * 64 + j * 16 + (lane & 15)] = f2bf(acc[j][r] * inv);
  }
  __syncthreads();

  // ---- P2Q row-major store
  for (int k = 0; k < 2; ++k) {
    int idx = t + k * 1024;
    int row = idx >> 5, c8 = idx & 31;
    *(int4*)&P2Q[((size_t)b * PLEN + p0 + row) * QLEN + c8 * 8] = *(const int4*)&Pl[row][c8 * 8];
  }
  // ---- P2Qt transposed store
  {
    int q = t >> 2, pcc = t & 3;
    u16x16 o;
    for (int e = 0; e < 16; ++e) o.u[e] = Pl[pcc * 16 + e][q];
    unsigned short* dst = P2Qt + ((size_t)b * QLEN + q) * PLEN + p0 + pcc * 16;
    *(int4*)dst = o.v[0];
    *(int4*)(dst + 8) = o.v[1];
  }

  // ---- QbT production (tile 0..3 only)
  if (tile < 4) {
    __syncthreads();
    int r0 = tile * 64;
    const float* src = question + ((size_t)b * QLEN + r0) * DIM;
    int row = t >> 4, c0 = (t & 15) * 16;
    for (int i = 0; i < 4; ++i) {
      int d = c0 + i * 4;
      float4 x = *(const float4*)&src[(size_t)row * DIM + d];
      u4x16 tv;
      tv.u[0] = f2bf(x.x); tv.u[1] = f2bf(x.y); tv.u[2] = f2bf(x.z); tv.u[3] = f2bf(x.w);
      *(int2*)&Pl[row][d] = tv.v;
    }
    __syncthreads();
    for (int it = 0; it < 2; ++it) {
      int g = t + it * 1024;
      int d = g >> 3, ch = g & 7;
      u8x16 o;
      for (int e = 0; e < 8; ++e) o.u[e] = Pl[ch * 8 + e][d];
      *(int4*)&QbT[(size_t)(b * DIM + d) * QLEN + r0 + ch * 8] = o.v;
    }
  }
}

// ---------------- k_mid (512 thr, grid NB*48): heterogeneous overlap.
// Blocks [0, 256): qatt2 (factored scales W2 = P2Q*RS[p]*CS[q], dbuf).
// Blocks [256, 768): out1 = P2Q @ QbT^T (64p x 128d tiles, 2/CU).
__global__ __launch_bounds__(512) void k_mid(
    const unsigned short* __restrict__ P2Qt, const unsigned short* __restrict__ PbT,
    const unsigned short* __restrict__ P2Q, const unsigned short* __restrict__ QbT,
    const float* __restrict__ RS, const float* __restrict__ CL,
    unsigned short* __restrict__ QATTt, float* __restrict__ out1) {
  __shared__ __align__(16) char smem[40960];
  int t = threadIdx.x, lane = t & 63, wid = t >> 6;

  if (blockIdx.x < NB * 16) {
    // ======== qatt2 ========
    int bid = blockIdx.x;
    int b = bid >> 4, dt = (bid >> 2) & 3, qt = bid & 3;
    int wm = wid >> 2, wn = wid & 3;                 // wave = 32 d x 16 q
    typedef unsigned short row72[72];
    row72* Wt = (row72*)smem;                        // [2][64][72]
    row72* At = (row72*)(smem + 18432);              // [2][64][72]
    float* CSs = (float*)(smem + 36864);
    if (t < 64) {
      int q = qt * 64 + t;
      float L = 0.f;
      for (int tm = 0; tm < 16; ++tm)
        L += CL[((size_t)b * 16 + tm) * QLEN + q];
      CSs[t] = (L > 0.f) ? 1.0f / L : 0.0f;          // masked column -> 0
    }

    int rrow = t >> 3;
    int pch = (t & 7) * 8;
    const unsigned short* Wsrc = P2Qt + ((size_t)b * QLEN + qt * 64 + rrow) * PLEN + pch;
    const unsigned short* Asrc = PbT + ((size_t)b * DIM + dt * 64 + rrow) * PLEN + pch;
    const float* rsB = RS + (size_t)b * PLEN + pch;

    f32x4 acc[2] = {};
    int4 wvv = *(const int4*)Wsrc;
    int4 av = *(const int4*)Asrc;
    float4 rs0 = *(const float4*)rsB, rs1 = *(const float4*)(rsB + 4);
    __syncthreads();
    float cs = CSs[rrow];

    {
      float rsv[8] = {rs0.x, rs0.y, rs0.z, rs0.w, rs1.x, rs1.y, rs1.z, rs1.w};
      const unsigned short* wu = (const unsigned short*)&wvv;
      u8x16 wo;
#pragma unroll
      for (int e = 0; e < 8; ++e) wo.u[e] = f2bf(bf2f(wu[e]) * rsv[e] * cs);
      *(int4*)&Wt[rrow][pch] = wo.v;
      *(int4*)&At[rrow][pch] = av;
    }
    __syncthreads();
    int cur = 0;
    for (int ps = 0; ps < 16; ++ps) {
      if (ps < 15) {
        int off = (ps + 1) * 64;
        wvv = *(const int4*)(Wsrc + off);
        av = *(const int4*)(Asrc + off);
        rs0 = *(const float4*)(rsB + off); rs1 = *(const float4*)(rsB + off + 4);
      }
      for (int kk = 0; kk < 64; kk += 32) {
        short8 bf = *(const short8*)&Wt[cur * 64 + wn * 16 + (lane & 15)][kk + (lane >> 4) * 8];
        for (int i = 0; i < 2; ++i) {
          short8 af = *(const short8*)&At[cur * 64 + wm * 32 + i * 16 + (lane & 15)][kk + (lane >> 4) * 8];
          acc[i] = __builtin_amdgcn_mfma_f32_16x16x32_bf16(af, bf, acc[i], 0, 0, 0);
        }
      }
      if (ps < 15) {
        float rsv[8] = {rs0.x, rs0.y, rs0.z, rs0.w, rs1.x, rs1.y, rs1.z, rs1.w};
        const unsigned short* wu = (const unsigned short*)&wvv;
        u8x16 wo;
#pragma unroll
        for (int e = 0; e < 8; ++e) wo.u[e] = f2bf(bf2f(wu[e]) * rsv[e] * cs);
        int nxt = cur ^ 1;
        *(int4*)&Wt[nxt * 64 + rrow][pch] = wo.v;
        *(int4*)&At[nxt * 64 + rrow][pch] = av;
        cur = nxt;
      }
      __syncthreads();
    }
    int d0 = dt * 64 + wm * 32, q0 = qt * 64 + wn * 16;
    for (int i = 0; i < 2; ++i)
      for (int rr = 0; rr < 4; ++rr) {
        int d = d0 + i * 16 + (lane >> 4) * 4 + rr;
        QATTt[((size_t)b * DIM + d) * QLEN + q0 + (lane & 15)] = f2bf(acc[i][rr]);
      }
  } else {
    // ======== out1 = P2Q @ QbT^T (64p x 128d) ========
    int u = blockIdx.x - NB * 16;
    int b = u >> 5, tm = (u >> 1) & 15, tn = u & 1;
    const unsigned short* A  = P2Q + ((size_t)b * PLEN + tm * 64) * QLEN;
    const unsigned short* B1 = QbT + ((size_t)b * DIM + tn * 128) * QLEN;
    typedef unsigned short row40[40];
    row40* As2 = (row40*)smem;                 // [2][64][40]  = 10240 B
    row40* Bq = (row40*)(smem + 10240);        // [2][128][40] = 20480 B
    int wm = wid >> 2, wn = wid & 3;           // wave = 32 p x 32 d
    f32x4 acc1[2][2] = {};
    int r = t >> 2, c = (t & 3) * 8;           // B: 128x32 (all threads); A: 64x32 (t<256)
    int4 rb1 = *(const int4*)&B1[(size_t)r * QLEN + c];
    int4 rav;
    if (t < 256) rav = *(const int4*)&A[(size_t)r * QLEN + c];
    *(int4*)&Bq[r][c] = rb1;
    if (t < 256) *(int4*)&As2[r][c] = rav;
    __syncthreads();
    int cur = 0;
    for (int ki = 0; ki < 8; ++ki) {
      if (ki < 7) {
        int kt = (ki + 1) * 32;
        rb1 = *(const int4*)&B1[(size_t)r * QLEN + kt + c];
        if (t < 256) rav = *(const int4*)&A[(size_t)r * QLEN + kt + c];
      }
      short8 af[2], b1v[2];
      for (int i = 0; i < 2; ++i)
        af[i] = *(const short8*)&As2[cur * 64 + wm * 32 + i * 16 + (lane & 15)][(lane >> 4) * 8];
      for (int j = 0; j < 2; ++j)
        b1v[j] = *(const short8*)&Bq[cur * 128 + wn * 32 + j * 16 + (lane & 15)][(lane >> 4) * 8];
      for (int i = 0; i < 2; ++i)
        for (int j = 0; j < 2; ++j)
          acc1[i][j] = __builtin_amdgcn_mfma_f32_16x16x32_bf16(af[i], b1v[j], acc1[i][j], 0, 0, 0);
      if (ki < 7) {
        int nxt = cur ^ 1;
        *(int4*)&Bq[nxt * 128 + r][c] = rb1;
        if (t < 256) *(int4*)&As2[nxt * 64 + r][c] = rav;
        cur = nxt;
      }
      __syncthreads();
    }
    int p0 = tm * 64 + wm * 32, d0 = tn * 128 + wn * 32;
    for (int i = 0; i < 2; ++i)
      for (int rr = 0; rr < 4; ++rr) {
        int p = p0 + i * 16 + (lane >> 4) * 4 + rr;
        size_t rowo = ((size_t)b * PLEN + p) * DIM;
        for (int j = 0; j < 2; ++j) {
          int d = d0 + j * 16 + (lane & 15);
          out1[rowo + d] = acc1[i][j][rr];
        }
      }
  }
}

// ---------------- k_final2 (512 thr, grid NB*32): out2 = P2Q @ QATTt^T; 64p x 128d, dbuf
__global__ __launch_bounds__(512) void k_final2(
    const unsigned short* __restrict__ P2Q, const unsigned short* __restrict__ QATTt,
    float* __restrict__ out2) {
  int bid = blockIdx.x;
  int b = bid >> 5, tm = (bid >> 1) & 15, tn = bid & 1;
  const unsigned short* A  = P2Q + ((size_t)b * PLEN + tm * 64) * QLEN;
  const unsigned short* B2 = QATTt + ((size_t)b * DIM + tn * 128) * QLEN;
  __shared__ __align__(16) unsigned short As[2][64][40];
  __shared__ __align__(16) unsigned short Bc[2][128][40];
  int t = threadIdx.x, lane = t & 63, wid = t >> 6;
  int wm = wid >> 2, wn = wid & 3;       // wave = 32 p x 32 d
  f32x4 acc[2][2] = {};
  int r = t >> 2, c = (t & 3) * 8;
  int4 rb2 = *(const int4*)&B2[(size_t)r * QLEN + c];
  int4 rav;
  if (t < 256) rav = *(const int4*)&A[(size_t)r * QLEN + c];
  *(int4*)&Bc[0][r][c] = rb2;
  if (t < 256) *(int4*)&As[0][r][c] = rav;
  __syncthreads();
  int cur = 0;
  for (int ki = 0; ki < 8; ++ki) {
    if (ki < 7) {
      int kt = (ki + 1) * 32;
      rb2 = *(const int4*)&B2[(size_t)r * QLEN + kt + c];
      if (t < 256) rav = *(const int4*)&A[(size_t)r * QLEN + kt + c];
    }
    short8 af[2], bc[2];
    for (int i = 0; i < 2; ++i)
      af[i] = *(const short8*)&As[cur][wm * 32 + i * 16 + (lane & 15)][(lane >> 4) * 8];
    for (int j = 0; j < 2; ++j)
      bc[j] = *(const short8*)&Bc[cur][wn * 32 + j * 16 + (lane & 15)][(lane >> 4) * 8];
    for (int i = 0; i < 2; ++i)
      for (int j = 0; j < 2; ++j)
        acc[i][j] = __builtin_amdgcn_mfma_f32_16x16x32_bf16(af[i], bc[j], acc[i][j], 0, 0, 0);
    if (ki < 7) {
      int nxt = cur ^ 1;
      *(int4*)&Bc[nxt][r][c] = rb2;
      if (t < 256) *(int4*)&As[nxt][r][c] = rav;
      cur = nxt;
    }
    __syncthreads();
  }
  int p0 = tm * 64 + wm * 32, d0 = tn * 128 + wn * 32;
  for (int i = 0; i < 2; ++i)
    for (int rr = 0; rr < 4; ++rr) {
      int p = p0 + i * 16 + (lane >> 4) * 4 + rr;
      size_t rowo = ((size_t)b * PLEN + p) * DIM;
      for (int j = 0; j < 2; ++j) {
        int d = d0 + j * 16 + (lane & 15);
        out2[rowo + d] = acc[i][j][rr];
      }
    }
}

extern "C" void kernel_launch(void* const* d_in, const int* in_sizes, int n_in,
                              void* d_out, int out_size, void* d_ws, size_t ws_size,
                              hipStream_t stream) {
  const float* passage  = (const float*)d_in[0];
  const float* question = (const float*)d_in[1];
  const int*   pmask    = (const int*)d_in[2];
  const int*   qmask    = (const int*)d_in[3];
  const float* W        = (const float*)d_in[4];
  const float* bias     = (const float*)d_in[5];
  float* out = (float*)d_out;

  const size_t NS = (size_t)NB * PLEN * QLEN;    // 4,194,304
  const size_t NQ = (size_t)NB * QLEN * DIM;     // 1,048,576
  char* w = (char*)d_ws;
  unsigned short* PbT  = (unsigned short*)w; w += NS * 2;
  unsigned short* QbT  = (unsigned short*)w; w += NQ * 2;
  unsigned short* P2Q  = (unsigned short*)w; w += NS * 2;
  unsigned short* P2Qt = (unsigned short*)w; w += NS * 2;
  unsigned short* QATTt = (unsigned short*)w; w += NQ * 2;
  float* CL = (float*)w;                     w += (size_t)NB * 16 * QLEN * 4;
  float* RS = (float*)w;

  float* out1 = out;
  float* out2 = out + (size_t)NB * PLEN * DIM;

  k_scoreA<<<dim3(NB * 16), dim3(1024), 0, stream>>>(
      passage, question, W, pmask, qmask, bias, PbT, QbT, CL, RS, P2Q, P2Qt);
  k_mid<<<dim3(NB * 48), dim3(512), 0, stream>>>(
      P2Qt, PbT, P2Q, QbT, RS, CL, QATTt, out1);
  k_final2<<<dim3(NB * 32), dim3(512), 0, stream>>>(
      P2Q, QATTt, out2);
}

// Round 18
// 51.993 us; speedup vs baseline: 1.1306x; 1.0305x over previous
//
#include <hip/hip_runtime.h>
#include <math.h>

#define NB 16
#define PLEN 1024
#define QLEN 256
#define DIM 256
#define MASKV -10000000.0f

typedef __attribute__((ext_vector_type(8))) short short8;
typedef __attribute__((ext_vector_type(4))) float f32x4;

union u4x16 { unsigned short u[4]; int2 v; };
union u8x16 { unsigned short u[8]; int4 v; };
union u16x16 { unsigned short u[16]; int4 v[2]; };

__device__ inline unsigned short f2bf(float x) {
  unsigned int u = __float_as_uint(x);
  u += 0x7FFF + ((u >> 16) & 1);          // round-to-nearest-even
  return (unsigned short)(u >> 16);
}
__device__ inline float bf2f(unsigned short u) {
  return __uint_as_float(((unsigned int)u) << 16);
}
__device__ inline int4 pack8(float4 a, float4 b) {
  u8x16 o;
  o.u[0] = f2bf(a.x); o.u[1] = f2bf(a.y); o.u[2] = f2bf(a.z); o.u[3] = f2bf(a.w);
  o.u[4] = f2bf(b.x); o.u[5] = f2bf(b.y); o.u[6] = f2bf(b.z); o.u[7] = f2bf(b.w);
  return o.v;
}

typedef unsigned short row40[40];
typedef unsigned short row136[136];
typedef unsigned short row264[264];

// LDS layout (51456 B total; TT(0..33792) reused over As/Bs/red* in end phases):
//   As   @     0  (2*64*40*2  = 10240)
//   Bs   @ 10240  (2*128*40*2 = 20480)
//   redL @ 30720  (4*128*4    =  2048)
//   rowL @ 32768  (64*2*4     =   512)
//   spS  @ 33280  (64*4       =   256)
//   sqS  @ 33536  (128*4      =   512)
//   Pl   @ 34048  (64*136*2   = 17408)  -> end 51456
#define SM_AS   0
#define SM_BS   10240
#define SM_REDL 30720
#define SM_ROWL 32768
#define SM_SPS  33280
#define SM_SQS  33536
#define SM_PL   34048
#define SM_TOT  51456

// ---------------- k_scoreA (grid 512, 512 thr = 8 waves, 2 blocks/CU):
// 64p x 128q half-tile. Inline prep + score GEMM + mask + exp.
// Outputs: E (unnormalized exp, row-major), Et (transposed), CL (col partial sums),
//          RS2 (row partial sums, [p][2]), PbT (qh==0 end phase), QbT (qh==1,tile<4).
__global__ __launch_bounds__(512, 4) void k_scoreA(
    const float* __restrict__ passage, const float* __restrict__ question,
    const float* __restrict__ Wg,
    const int* __restrict__ pmask, const int* __restrict__ qmask,
    const float* __restrict__ bias,
    unsigned short* __restrict__ PbT, unsigned short* __restrict__ QbT,
    float* __restrict__ CL, float* __restrict__ RS2,
    unsigned short* __restrict__ E, unsigned short* __restrict__ Et) {
  __shared__ __align__(16) char smem[SM_TOT];
  row40* As = (row40*)(smem + SM_AS);            // [2*64]
  row40* Bs = (row40*)(smem + SM_BS);            // [2*128]
  float (*redL)[128] = (float(*)[128])(smem + SM_REDL);
  float (*rowL)[2] = (float(*)[2])(smem + SM_ROWL);
  float* spS = (float*)(smem + SM_SPS);
  float* sqS = (float*)(smem + SM_SQS);
  row136* Pl = (row136*)(smem + SM_PL);          // [64]

  int bid0 = blockIdx.x;
  int bid = (bid0 & 7) * 64 + (bid0 >> 3);       // chunked XCD swizzle, bijective for 512
  int b = bid >> 5;
  int tile = (bid >> 1) & 15;
  int qh = bid & 1;
  int p0 = tile * 64, q0 = qh * 128;
  int t = threadIdx.x, lane = t & 63, wv = t >> 6;   // 8 waves
  int s = wv >> 1, h = wv & 1;                   // p-strip 0..3 (16 rows), q-half 0..1 (64 q)

  int rb = t >> 2, cb = (t & 3) * 8;             // Bs staging: 128 rows x 32 (int4)
  int pr = t >> 3, pc = (t & 7) * 4;             // As staging: 64 rows x 32 (int2)
  const float* psrc = passage + ((size_t)b * PLEN + p0 + pr) * DIM;
  const float* qsrc = question + ((size_t)b * QLEN + q0 + rb) * DIM;
  const float* wq = Wg + DIM;
  const float* wpq = Wg + 2 * DIM;

  // ---- phase 1: inline-prep + score GEMM (64 x 128, K = 256), dbuf
  f32x4 acc[4] = {};
  float spp = 0.f, sqq = 0.f;
  {
    float4 qa = *(const float4*)&qsrc[cb];
    float4 qb_ = *(const float4*)&qsrc[cb + 4];
    float4 x = *(const float4*)&psrc[pc];
    sqq += qa.x * wq[cb]     + qa.y * wq[cb + 1] + qa.z * wq[cb + 2] + qa.w * wq[cb + 3]
         + qb_.x * wq[cb + 4] + qb_.y * wq[cb + 5] + qb_.z * wq[cb + 6] + qb_.w * wq[cb + 7];
    spp += x.x * Wg[pc] + x.y * Wg[pc + 1] + x.z * Wg[pc + 2] + x.w * Wg[pc + 3];
    *(int4*)&Bs[0 * 128 + rb][cb] = pack8(qa, qb_);
    u4x16 wg4;
    wg4.u[0] = f2bf(x.x * wpq[pc]);     wg4.u[1] = f2bf(x.y * wpq[pc + 1]);
    wg4.u[2] = f2bf(x.z * wpq[pc + 2]); wg4.u[3] = f2bf(x.w * wpq[pc + 3]);
    *(int2*)&As[0 * 64 + pr][pc] = wg4.v;
  }
  __syncthreads();
  int cur = 0;
  for (int ki = 0; ki < 8; ++ki) {
    float4 qa2, qb2, xn;
    if (ki < 7) {
      int kt = (ki + 1) * 32;
      qa2 = *(const float4*)&qsrc[kt + cb];
      qb2 = *(const float4*)&qsrc[kt + cb + 4];
      xn = *(const float4*)&psrc[kt + pc];
    }
    short8 af = *(const short8*)&As[cur * 64 + s * 16 + (lane & 15)][(lane >> 4) * 8];
    for (int j = 0; j < 4; ++j) {
      short8 bf = *(const short8*)&Bs[cur * 128 + h * 64 + j * 16 + (lane & 15)][(lane >> 4) * 8];
      acc[j] = __builtin_amdgcn_mfma_f32_16x16x32_bf16(af, bf, acc[j], 0, 0, 0);
    }
    if (ki < 7) {
      int kt = (ki + 1) * 32;
      int dq = kt + cb, dp = kt + pc;
      sqq += qa2.x * wq[dq]     + qa2.y * wq[dq + 1] + qa2.z * wq[dq + 2] + qa2.w * wq[dq + 3]
           + qb2.x * wq[dq + 4] + qb2.y * wq[dq + 5] + qb2.z * wq[dq + 6] + qb2.w * wq[dq + 7];
      spp += xn.x * Wg[dp] + xn.y * Wg[dp + 1] + xn.z * Wg[dp + 2] + xn.w * Wg[dp + 3];
      int nxt = cur ^ 1;
      *(int4*)&Bs[nxt * 128 + rb][cb] = pack8(qa2, qb2);
      u4x16 wg4;
      wg4.u[0] = f2bf(xn.x * wpq[dp]);     wg4.u[1] = f2bf(xn.y * wpq[dp + 1]);
      wg4.u[2] = f2bf(xn.z * wpq[dp + 2]); wg4.u[3] = f2bf(xn.w * wpq[dp + 3]);
      *(int2*)&As[nxt * 64 + pr][pc] = wg4.v;
      cur = nxt;
    }
    __syncthreads();
  }

  // ---- reduces: sq (4 thr/row), sp (8 thr/row)
  sqq += __shfl_xor(sqq, 1, 64);
  sqq += __shfl_xor(sqq, 2, 64);
  if ((t & 3) == 0) sqS[rb] = sqq;
  spp += __shfl_xor(spp, 1, 64);
  spp += __shfl_xor(spp, 2, 64);
  spp += __shfl_xor(spp, 4, 64);
  if ((t & 7) == 0) spS[pr] = spp;
  __syncthreads();

  // ---- epilogue: bias + mask -> exp-space; partial sums; E into Pl
  float b0 = bias[0];
  float spv[4]; int pmv[4];
  for (int r = 0; r < 4; ++r) {
    int rl = s * 16 + (lane >> 4) * 4 + r;
    spv[r] = spS[rl] + b0;
    pmv[r] = pmask[b * PLEN + p0 + rl];
  }
  float sqv[4]; int qmv[4];
  for (int j = 0; j < 4; ++j) {
    int ql = h * 64 + j * 16 + (lane & 15);
    sqv[j] = sqS[ql];
    qmv[j] = qmask[b * QLEN + q0 + ql];
  }
  for (int j = 0; j < 4; ++j)
    for (int r = 0; r < 4; ++r) {
      float v = acc[j][r] + spv[r] + sqv[j];
      acc[j][r] = (pmv[r] | qmv[j]) ? 0.0f : __expf(v);
    }
  for (int j = 0; j < 4; ++j) {
    float e = acc[j][0] + acc[j][1] + acc[j][2] + acc[j][3];
    e += __shfl_xor(e, 16, 64);
    e += __shfl_xor(e, 32, 64);
    if ((lane >> 4) == 0)
      redL[s][h * 64 + j * 16 + (lane & 15)] = e;
  }
  for (int r = 0; r < 4; ++r) {
    int rl = s * 16 + (lane >> 4) * 4 + r;
    float l = acc[0][r] + acc[1][r] + acc[2][r] + acc[3][r];
    for (int msk = 1; msk <= 8; msk <<= 1) l += __shfl_xor(l, msk, 64);
    if ((lane & 15) == 0) rowL[rl][h] = l;
  }
  for (int r = 0; r < 4; ++r) {
    int rl = s * 16 + (lane >> 4) * 4 + r;
    for (int j = 0; j < 4; ++j)
      Pl[rl][h * 64 + j * 16 + (lane & 15)] = f2bf(acc[j][r]);
  }
  __syncthreads();

  // ---- CL (128 q entries) + RS2 (64 row partials)
  if (t < 128) {
    CL[((size_t)b * 16 + tile) * QLEN + q0 + t] = redL[0][t] + redL[1][t] + redL[2][t] + redL[3][t];
  } else if (t < 192) {
    int rl = t - 128;
    RS2[((size_t)b * PLEN + p0 + rl) * 2 + qh] = rowL[rl][0] + rowL[rl][1];
  }

  // ---- E row-major store (64 x 128)
  for (int k = 0; k < 2; ++k) {
    int idx = t + k * 512;
    int row = idx >> 4, c8 = idx & 15;
    *(int4*)&E[((size_t)b * PLEN + p0 + row) * QLEN + q0 + c8 * 8] = *(const int4*)&Pl[row][c8 * 8];
  }
  // ---- Et transposed store (128 q rows x 64 p)
  {
    int ql = t >> 2, pcc = t & 3;
    u16x16 o;
    for (int e = 0; e < 16; ++e) o.u[e] = Pl[pcc * 16 + e][ql];
    unsigned short* dst = Et + ((size_t)b * QLEN + q0 + ql) * PLEN + p0 + pcc * 16;
    *(int4*)dst = o.v[0];
    *(int4*)(dst + 8) = o.v[1];
  }
  __syncthreads();   // redL/rowL/spS/sqS reads done -> TT may reuse

  // ---- end phases: PbT (qh==0) / QbT (qh==1 && tile<4), via TT union buffer
  row264* TT = (row264*)smem;                    // 64 x 264 = 33792 B (over As/Bs/red*)
  if (qh == 0) {
    const float* src = passage + ((size_t)b * PLEN + p0) * DIM;
    int row = t >> 3, c0 = (t & 7) * 32;
    for (int i = 0; i < 8; ++i) {
      int d = c0 + i * 4;
      float4 x = *(const float4*)&src[(size_t)row * DIM + d];
      u4x16 tv;
      tv.u[0] = f2bf(x.x); tv.u[1] = f2bf(x.y); tv.u[2] = f2bf(x.z); tv.u[3] = f2bf(x.w);
      *(int2*)&TT[row][d] = tv.v;
    }
    __syncthreads();
    for (int it = 0; it < 4; ++it) {
      int g = t + it * 512;
      int dd = g >> 3, ch = g & 7;
      u8x16 o;
      for (int e = 0; e < 8; ++e) o.u[e] = TT[ch * 8 + e][dd];
      *(int4*)&PbT[((size_t)b * DIM + dd) * PLEN + p0 + ch * 8] = o.v;
    }
  } else if (tile < 4) {
    int r0 = tile * 64;
    const float* src = question + ((size_t)b * QLEN + r0) * DIM;
    int row = t >> 3, c0 = (t & 7) * 32;
    for (int i = 0; i < 8; ++i) {
      int d = c0 + i * 4;
      float4 x = *(const float4*)&src[(size_t)row * DIM + d];
      u4x16 tv;
      tv.u[0] = f2bf(x.x); tv.u[1] = f2bf(x.y); tv.u[2] = f2bf(x.z); tv.u[3] = f2bf(x.w);
      *(int2*)&TT[row][d] = tv.v;
    }
    __syncthreads();
    for (int it = 0; it < 4; ++it) {
      int g = t + it * 512;
      int dd = g >> 3, ch = g & 7;
      u8x16 o;
      for (int e = 0; e < 8; ++e) o.u[e] = TT[ch * 8 + e][dd];
      *(int4*)&QbT[((size_t)b * DIM + dd) * QLEN + r0 + ch * 8] = o.v;
    }
  }
}

// ---------------- k_mid (512 thr, grid NB*48): heterogeneous overlap.
// Blocks [0, 256): qatt2 — W2 = E * CS[q] (RS cancels), dbuf, no exp.
// Blocks [256, 768): out1 = (1/RS) * E @ QbT^T (64p x 128d tiles).
__global__ __launch_bounds__(512) void k_mid(
    const unsigned short* __restrict__ Et, const unsigned short* __restrict__ PbT,
    const unsigned short* __restrict__ E, const unsigned short* __restrict__ QbT,
    const float* __restrict__ RS2, const float* __restrict__ CL,
    unsigned short* __restrict__ QATTt, float* __restrict__ out1) {
  __shared__ __align__(16) char smem[40960];
  int t = threadIdx.x, lane = t & 63, wid = t >> 6;

  if (blockIdx.x < NB * 16) {
    // ======== qatt2 ========
    int bid = blockIdx.x;
    int b = bid >> 4, dt = (bid >> 2) & 3, qt = bid & 3;
    int wm = wid >> 2, wn = wid & 3;                 // wave = 32 d x 16 q
    typedef unsigned short row72[72];
    row72* Wt = (row72*)smem;                        // [2][64][72]
    row72* At = (row72*)(smem + 18432);              // [2][64][72]
    float* CSs = (float*)(smem + 36864);
    if (t < 64) {
      int q = qt * 64 + t;
      float L = 0.f;
      for (int tm = 0; tm < 16; ++tm)
        L += CL[((size_t)b * 16 + tm) * QLEN + q];
      CSs[t] = (L > 0.f) ? 1.0f / L : 0.0f;          // masked column -> 0
    }

    int rrow = t >> 3;
    int pch = (t & 7) * 8;
    const unsigned short* Wsrc = Et + ((size_t)b * QLEN + qt * 64 + rrow) * PLEN + pch;
    const unsigned short* Asrc = PbT + ((size_t)b * DIM + dt * 64 + rrow) * PLEN + pch;

    f32x4 acc[2] = {};
    int4 wvv = *(const int4*)Wsrc;
    int4 av = *(const int4*)Asrc;
    __syncthreads();
    float cs = CSs[rrow];

    {
      const unsigned short* wu = (const unsigned short*)&wvv;
      u8x16 wo;
#pragma unroll
      for (int e = 0; e < 8; ++e) wo.u[e] = f2bf(bf2f(wu[e]) * cs);
      *(int4*)&Wt[rrow][pch] = wo.v;
      *(int4*)&At[rrow][pch] = av;
    }
    __syncthreads();
    int cur = 0;
    for (int ps = 0; ps < 16; ++ps) {
      if (ps < 15) {
        int off = (ps + 1) * 64;
        wvv = *(const int4*)(Wsrc + off);
        av = *(const int4*)(Asrc + off);
      }
      for (int kk = 0; kk < 64; kk += 32) {
        short8 bf = *(const short8*)&Wt[cur * 64 + wn * 16 + (lane & 15)][kk + (lane >> 4) * 8];
        for (int i = 0; i < 2; ++i) {
          short8 af = *(const short8*)&At[cur * 64 + wm * 32 + i * 16 + (lane & 15)][kk + (lane >> 4) * 8];
          acc[i] = __builtin_amdgcn_mfma_f32_16x16x32_bf16(af, bf, acc[i], 0, 0, 0);
        }
      }
      if (ps < 15) {
        const unsigned short* wu = (const unsigned short*)&wvv;
        u8x16 wo;
#pragma unroll
        for (int e = 0; e < 8; ++e) wo.u[e] = f2bf(bf2f(wu[e]) * cs);
        int nxt = cur ^ 1;
        *(int4*)&Wt[nxt * 64 + rrow][pch] = wo.v;
        *(int4*)&At[nxt * 64 + rrow][pch] = av;
        cur = nxt;
      }
      __syncthreads();
    }
    int d0 = dt * 64 + wm * 32, q0 = qt * 64 + wn * 16;
    for (int i = 0; i < 2; ++i)
      for (int rr = 0; rr < 4; ++rr) {
        int d = d0 + i * 16 + (lane >> 4) * 4 + rr;
        QATTt[((size_t)b * DIM + d) * QLEN + q0 + (lane & 15)] = f2bf(acc[i][rr]);
      }
  } else {
    // ======== out1 = (1/RS) * E @ QbT^T (64p x 128d) ========
    int u = blockIdx.x - NB * 16;
    int b = u >> 5, tm = (u >> 1) & 15, tn = u & 1;
    const unsigned short* A  = E + ((size_t)b * PLEN + tm * 64) * QLEN;
    const unsigned short* B1 = QbT + ((size_t)b * DIM + tn * 128) * QLEN;
    typedef unsigned short row40k[40];
    row40k* As2 = (row40k*)smem;               // [2][64][40]  = 10240
    row40k* Bq = (row40k*)(smem + 10240);      // [2][128][40] = 20480
    float* invS = (float*)(smem + 30720);      // 64 floats
    int wm = wid >> 2, wn = wid & 3;           // wave = 32 p x 32 d
    if (t < 64) {
      float rs = RS2[((size_t)b * PLEN + tm * 64 + t) * 2]
               + RS2[((size_t)b * PLEN + tm * 64 + t) * 2 + 1];
      invS[t] = (rs > 0.f) ? 1.0f / rs : 0.0f;
    }
    f32x4 acc1[2][2] = {};
    int r = t >> 2, c = (t & 3) * 8;
    int4 rb1 = *(const int4*)&B1[(size_t)r * QLEN + c];
    int4 rav;
    if (t < 256) rav = *(const int4*)&A[(size_t)r * QLEN + c];
    *(int4*)&Bq[r][c] = rb1;
    if (t < 256) *(int4*)&As2[r][c] = rav;
    __syncthreads();
    int cur = 0;
    for (int ki = 0; ki < 8; ++ki) {
      if (ki < 7) {
        int kt = (ki + 1) * 32;
        rb1 = *(const int4*)&B1[(size_t)r * QLEN + kt + c];
        if (t < 256) rav = *(const int4*)&A[(size_t)r * QLEN + kt + c];
      }
      short8 af[2], b1v[2];
      for (int i = 0; i < 2; ++i)
        af[i] = *(const short8*)&As2[cur * 64 + wm * 32 + i * 16 + (lane & 15)][(lane >> 4) * 8];
      for (int j = 0; j < 2; ++j)
        b1v[j] = *(const short8*)&Bq[cur * 128 + wn * 32 + j * 16 + (lane & 15)][(lane >> 4) * 8];
      for (int i = 0; i < 2; ++i)
        for (int j = 0; j < 2; ++j)
          acc1[i][j] = __builtin_amdgcn_mfma_f32_16x16x32_bf16(af[i], b1v[j], acc1[i][j], 0, 0, 0);
      if (ki < 7) {
        int nxt = cur ^ 1;
        *(int4*)&Bq[nxt * 128 + r][c] = rb1;
        if (t < 256) *(int4*)&As2[nxt * 64 + r][c] = rav;
        cur = nxt;
      }
      __syncthreads();
    }
    int p0 = tm * 64 + wm * 32, d0 = tn * 128 + wn * 32;
    for (int i = 0; i < 2; ++i)
      for (int rr = 0; rr < 4; ++rr) {
        int pl = wm * 32 + i * 16 + (lane >> 4) * 4 + rr;
        float inv = invS[pl];
        int p = tm * 64 + pl;
        size_t rowo = ((size_t)b * PLEN + p) * DIM;
        for (int j = 0; j < 2; ++j) {
          int d = d0 + j * 16 + (lane & 15);
          out1[rowo + d] = acc1[i][j][rr] * inv;
        }
      }
  }
}

// ---------------- k_final2 (512 thr, grid NB*32): out2 = (1/RS) * E @ QATTt^T; 64p x 128d
__global__ __launch_bounds__(512) void k_final2(
    const unsigned short* __restrict__ E, const unsigned short* __restrict__ QATTt,
    const float* __restrict__ RS2, float* __restrict__ out2) {
  int bid = blockIdx.x;
  int b = bid >> 5, tm = (bid >> 1) & 15, tn = bid & 1;
  const unsigned short* A  = E + ((size_t)b * PLEN + tm * 64) * QLEN;
  const unsigned short* B2 = QATTt + ((size_t)b * DIM + tn * 128) * QLEN;
  __shared__ __align__(16) unsigned short As[2][64][40];
  __shared__ __align__(16) unsigned short Bc[2][128][40];
  __shared__ float invS[64];
  int t = threadIdx.x, lane = t & 63, wid = t >> 6;
  int wm = wid >> 2, wn = wid & 3;       // wave = 32 p x 32 d
  if (t < 64) {
    float rs = RS2[((size_t)b * PLEN + tm * 64 + t) * 2]
             + RS2[((size_t)b * PLEN + tm * 64 + t) * 2 + 1];
    invS[t] = (rs > 0.f) ? 1.0f / rs : 0.0f;
  }
  f32x4 acc[2][2] = {};
  int r = t >> 2, c = (t & 3) * 8;
  int4 rb2 = *(const int4*)&B2[(size_t)r * QLEN + c];
  int4 rav;
  if (t < 256) rav = *(const int4*)&A[(size_t)r * QLEN + c];
  *(int4*)&Bc[0][r][c] = rb2;
  if (t < 256) *(int4*)&As[0][r][c] = rav;
  __syncthreads();
  int cur = 0;
  for (int ki = 0; ki < 8; ++ki) {
    if (ki < 7) {
      int kt = (ki + 1) * 32;
      rb2 = *(const int4*)&B2[(size_t)r * QLEN + kt + c];
      if (t < 256) rav = *(const int4*)&A[(size_t)r * QLEN + kt + c];
    }
    short8 af[2], bc[2];
    for (int i = 0; i < 2; ++i)
      af[i] = *(const short8*)&As[cur][wm * 32 + i * 16 + (lane & 15)][(lane >> 4) * 8];
    for (int j = 0; j < 2; ++j)
      bc[j] = *(const short8*)&Bc[cur][wn * 32 + j * 16 + (lane & 15)][(lane >> 4) * 8];
    for (int i = 0; i < 2; ++i)
      for (int j = 0; j < 2; ++j)
        acc[i][j] = __builtin_amdgcn_mfma_f32_16x16x32_bf16(af[i], bc[j], acc[i][j], 0, 0, 0);
    if (ki < 7) {
      int nxt = cur ^ 1;
      *(int4*)&Bc[nxt][r][c] = rb2;
      if (t < 256) *(int4*)&As[nxt][r][c] = rav;
      cur = nxt;
    }
    __syncthreads();
  }
  int d0 = tn * 128 + wn * 32;
  for (int i = 0; i < 2; ++i)
    for (int rr = 0; rr < 4; ++rr) {
      int pl = wm * 32 + i * 16 + (lane >> 4) * 4 + rr;
      float inv = invS[pl];
      int p = tm * 64 + pl;
      size_t rowo = ((size_t)b * PLEN + p) * DIM;
      for (int j = 0; j < 2; ++j) {
        int d = d0 + j * 16 + (lane & 15);
        out2[rowo + d] = acc[i][j][rr] * inv;
      }
    }
}

extern "C" void kernel_launch(void* const* d_in, const int* in_sizes, int n_in,
                              void* d_out, int out_size, void* d_ws, size_t ws_size,
                              hipStream_t stream) {
  const float* passage  = (const float*)d_in[0];
  const float* question = (const float*)d_in[1];
  const int*   pmask    = (const int*)d_in[2];
  const int*   qmask    = (const int*)d_in[3];
  const float* W        = (const float*)d_in[4];
  const float* bias     = (const float*)d_in[5];
  float* out = (float*)d_out;

  const size_t NS = (size_t)NB * PLEN * QLEN;    // 4,194,304
  const size_t NQ = (size_t)NB * QLEN * DIM;     // 1,048,576
  char* w = (char*)d_ws;
  unsigned short* PbT  = (unsigned short*)w; w += NS * 2;
  unsigned short* QbT  = (unsigned short*)w; w += NQ * 2;
  unsigned short* E    = (unsigned short*)w; w += NS * 2;
  unsigned short* Et   = (unsigned short*)w; w += NS * 2;
  unsigned short* QATTt = (unsigned short*)w; w += NQ * 2;
  float* CL  = (float*)w;                    w += (size_t)NB * 16 * QLEN * 4;
  float* RS2 = (float*)w;

  float* out1 = out;
  float* out2 = out + (size_t)NB * PLEN * DIM;

  k_scoreA<<<dim3(512), dim3(512), 0, stream>>>(
      passage, question, W, pmask, qmask, bias, PbT, QbT, CL, RS2, E, Et);
  k_mid<<<dim3(NB * 48), dim3(512), 0, stream>>>(
      Et, PbT, E, QbT, RS2, CL, QATTt, out1);
  k_final2<<<dim3(NB * 32), dim3(512), 0, stream>>>(
      E, QATTt, RS2, out2);
}

// Round 19
// 49.029 us; speedup vs baseline: 1.1990x; 1.0604x over previous
//
#include <hip/hip_runtime.h>
#include <math.h>

#define NB 16
#define PLEN 1024
#define QLEN 256
#define DIM 256
#define MASKV -10000000.0f

typedef __attribute__((ext_vector_type(8))) short short8;
typedef __attribute__((ext_vector_type(4))) float f32x4;

union u4x16 { unsigned short u[4]; int2 v; };
union u8x16 { unsigned short u[8]; int4 v; };
union u16x16 { unsigned short u[16]; int4 v[2]; };

__device__ inline unsigned short f2bf(float x) {
  unsigned int u = __float_as_uint(x);
  u += 0x7FFF + ((u >> 16) & 1);          // round-to-nearest-even
  return (unsigned short)(u >> 16);
}
__device__ inline float bf2f(unsigned short u) {
  return __uint_as_float(((unsigned int)u) << 16);
}
__device__ inline int4 pack8(float4 a, float4 b) {
  u8x16 o;
  o.u[0] = f2bf(a.x); o.u[1] = f2bf(a.y); o.u[2] = f2bf(a.z); o.u[3] = f2bf(a.w);
  o.u[4] = f2bf(b.x); o.u[5] = f2bf(b.y); o.u[6] = f2bf(b.z); o.u[7] = f2bf(b.w);
  return o.v;
}

typedef unsigned short row40[40];
typedef unsigned short row136[136];
typedef unsigned short row264[264];

#define SM_AS   0
#define SM_BS   10240
#define SM_REDL 30720
#define SM_ROWL 32768
#define SM_SPS  33280
#define SM_SQS  33536
#define SM_PL   34048
#define SM_TOT  51456

// ---------------- k_scoreA (grid 512, 512 thr, 2 blocks/CU): 64p x 128q half-tile.
__global__ __launch_bounds__(512, 4) void k_scoreA(
    const float* __restrict__ passage, const float* __restrict__ question,
    const float* __restrict__ Wg,
    const int* __restrict__ pmask, const int* __restrict__ qmask,
    const float* __restrict__ bias,
    unsigned short* __restrict__ PbT, unsigned short* __restrict__ QbT,
    float* __restrict__ CL, float* __restrict__ RS2,
    unsigned short* __restrict__ E, unsigned short* __restrict__ Et) {
  __shared__ __align__(16) char smem[SM_TOT];
  row40* As = (row40*)(smem + SM_AS);
  row40* Bs = (row40*)(smem + SM_BS);
  float (*redL)[128] = (float(*)[128])(smem + SM_REDL);
  float (*rowL)[2] = (float(*)[2])(smem + SM_ROWL);
  float* spS = (float*)(smem + SM_SPS);
  float* sqS = (float*)(smem + SM_SQS);
  row136* Pl = (row136*)(smem + SM_PL);

  int bid0 = blockIdx.x;
  int bid = (bid0 & 7) * 64 + (bid0 >> 3);       // chunked XCD swizzle, bijective for 512
  int b = bid >> 5;
  int tile = (bid >> 1) & 15;
  int qh = bid & 1;
  int p0 = tile * 64, q0 = qh * 128;
  int t = threadIdx.x, lane = t & 63, wv = t >> 6;   // 8 waves
  int s = wv >> 1, h = wv & 1;

  int rb = t >> 2, cb = (t & 3) * 8;
  int pr = t >> 3, pc = (t & 7) * 4;
  const float* psrc = passage + ((size_t)b * PLEN + p0 + pr) * DIM;
  const float* qsrc = question + ((size_t)b * QLEN + q0 + rb) * DIM;
  const float* wq = Wg + DIM;
  const float* wpq = Wg + 2 * DIM;

  f32x4 acc[4] = {};
  float spp = 0.f, sqq = 0.f;
  {
    float4 qa = *(const float4*)&qsrc[cb];
    float4 qb_ = *(const float4*)&qsrc[cb + 4];
    float4 x = *(const float4*)&psrc[pc];
    sqq += qa.x * wq[cb]     + qa.y * wq[cb + 1] + qa.z * wq[cb + 2] + qa.w * wq[cb + 3]
         + qb_.x * wq[cb + 4] + qb_.y * wq[cb + 5] + qb_.z * wq[cb + 6] + qb_.w * wq[cb + 7];
    spp += x.x * Wg[pc] + x.y * Wg[pc + 1] + x.z * Wg[pc + 2] + x.w * Wg[pc + 3];
    *(int4*)&Bs[0 * 128 + rb][cb] = pack8(qa, qb_);
    u4x16 wg4;
    wg4.u[0] = f2bf(x.x * wpq[pc]);     wg4.u[1] = f2bf(x.y * wpq[pc + 1]);
    wg4.u[2] = f2bf(x.z * wpq[pc + 2]); wg4.u[3] = f2bf(x.w * wpq[pc + 3]);
    *(int2*)&As[0 * 64 + pr][pc] = wg4.v;
  }
  __syncthreads();
  int cur = 0;
  for (int ki = 0; ki < 8; ++ki) {
    float4 qa2, qb2, xn;
    if (ki < 7) {
      int kt = (ki + 1) * 32;
      qa2 = *(const float4*)&qsrc[kt + cb];
      qb2 = *(const float4*)&qsrc[kt + cb + 4];
      xn = *(const float4*)&psrc[kt + pc];
    }
    short8 af = *(const short8*)&As[cur * 64 + s * 16 + (lane & 15)][(lane >> 4) * 8];
    for (int j = 0; j < 4; ++j) {
      short8 bf = *(const short8*)&Bs[cur * 128 + h * 64 + j * 16 + (lane & 15)][(lane >> 4) * 8];
      acc[j] = __builtin_amdgcn_mfma_f32_16x16x32_bf16(af, bf, acc[j], 0, 0, 0);
    }
    if (ki < 7) {
      int kt = (ki + 1) * 32;
      int dq = kt + cb, dp = kt + pc;
      sqq += qa2.x * wq[dq]     + qa2.y * wq[dq + 1] + qa2.z * wq[dq + 2] + qa2.w * wq[dq + 3]
           + qb2.x * wq[dq + 4] + qb2.y * wq[dq + 5] + qb2.z * wq[dq + 6] + qb2.w * wq[dq + 7];
      spp += xn.x * Wg[dp] + xn.y * Wg[dp + 1] + xn.z * Wg[dp + 2] + xn.w * Wg[dp + 3];
      int nxt = cur ^ 1;
      *(int4*)&Bs[nxt * 128 + rb][cb] = pack8(qa2, qb2);
      u4x16 wg4;
      wg4.u[0] = f2bf(xn.x * wpq[dp]);     wg4.u[1] = f2bf(xn.y * wpq[dp + 1]);
      wg4.u[2] = f2bf(xn.z * wpq[dp + 2]); wg4.u[3] = f2bf(xn.w * wpq[dp + 3]);
      *(int2*)&As[nxt * 64 + pr][pc] = wg4.v;
      cur = nxt;
    }
    __syncthreads();
  }

  sqq += __shfl_xor(sqq, 1, 64);
  sqq += __shfl_xor(sqq, 2, 64);
  if ((t & 3) == 0) sqS[rb] = sqq;
  spp += __shfl_xor(spp, 1, 64);
  spp += __shfl_xor(spp, 2, 64);
  spp += __shfl_xor(spp, 4, 64);
  if ((t & 7) == 0) spS[pr] = spp;
  __syncthreads();

  float b0 = bias[0];
  float spv[4]; int pmv[4];
  for (int r = 0; r < 4; ++r) {
    int rl = s * 16 + (lane >> 4) * 4 + r;
    spv[r] = spS[rl] + b0;
    pmv[r] = pmask[b * PLEN + p0 + rl];
  }
  float sqv[4]; int qmv[4];
  for (int j = 0; j < 4; ++j) {
    int ql = h * 64 + j * 16 + (lane & 15);
    sqv[j] = sqS[ql];
    qmv[j] = qmask[b * QLEN + q0 + ql];
  }
  for (int j = 0; j < 4; ++j)
    for (int r = 0; r < 4; ++r) {
      float v = acc[j][r] + spv[r] + sqv[j];
      acc[j][r] = (pmv[r] | qmv[j]) ? 0.0f : __expf(v);
    }
  for (int j = 0; j < 4; ++j) {
    float e = acc[j][0] + acc[j][1] + acc[j][2] + acc[j][3];
    e += __shfl_xor(e, 16, 64);
    e += __shfl_xor(e, 32, 64);
    if ((lane >> 4) == 0)
      redL[s][h * 64 + j * 16 + (lane & 15)] = e;
  }
  for (int r = 0; r < 4; ++r) {
    int rl = s * 16 + (lane >> 4) * 4 + r;
    float l = acc[0][r] + acc[1][r] + acc[2][r] + acc[3][r];
    for (int msk = 1; msk <= 8; msk <<= 1) l += __shfl_xor(l, msk, 64);
    if ((lane & 15) == 0) rowL[rl][h] = l;
  }
  for (int r = 0; r < 4; ++r) {
    int rl = s * 16 + (lane >> 4) * 4 + r;
    for (int j = 0; j < 4; ++j)
      Pl[rl][h * 64 + j * 16 + (lane & 15)] = f2bf(acc[j][r]);
  }
  __syncthreads();

  if (t < 128) {
    CL[((size_t)b * 16 + tile) * QLEN + q0 + t] = redL[0][t] + redL[1][t] + redL[2][t] + redL[3][t];
  } else if (t < 192) {
    int rl = t - 128;
    RS2[((size_t)b * PLEN + p0 + rl) * 2 + qh] = rowL[rl][0] + rowL[rl][1];
  }

  for (int k = 0; k < 2; ++k) {
    int idx = t + k * 512;
    int row = idx >> 4, c8 = idx & 15;
    *(int4*)&E[((size_t)b * PLEN + p0 + row) * QLEN + q0 + c8 * 8] = *(const int4*)&Pl[row][c8 * 8];
  }
  {
    int ql = t >> 2, pcc = t & 3;
    u16x16 o;
    for (int e = 0; e < 16; ++e) o.u[e] = Pl[pcc * 16 + e][ql];
    unsigned short* dst = Et + ((size_t)b * QLEN + q0 + ql) * PLEN + p0 + pcc * 16;
    *(int4*)dst = o.v[0];
    *(int4*)(dst + 8) = o.v[1];
  }
  __syncthreads();

  row264* TT = (row264*)smem;
  if (qh == 0) {
    const float* src = passage + ((size_t)b * PLEN + p0) * DIM;
    int row = t >> 3, c0 = (t & 7) * 32;
    for (int i = 0; i < 8; ++i) {
      int d = c0 + i * 4;
      float4 x = *(const float4*)&src[(size_t)row * DIM + d];
      u4x16 tv;
      tv.u[0] = f2bf(x.x); tv.u[1] = f2bf(x.y); tv.u[2] = f2bf(x.z); tv.u[3] = f2bf(x.w);
      *(int2*)&TT[row][d] = tv.v;
    }
    __syncthreads();
    for (int it = 0; it < 4; ++it) {
      int g = t + it * 512;
      int dd = g >> 3, ch = g & 7;
      u8x16 o;
      for (int e = 0; e < 8; ++e) o.u[e] = TT[ch * 8 + e][dd];
      *(int4*)&PbT[((size_t)b * DIM + dd) * PLEN + p0 + ch * 8] = o.v;
    }
  } else if (tile < 4) {
    int r0 = tile * 64;
    const float* src = question + ((size_t)b * QLEN + r0) * DIM;
    int row = t >> 3, c0 = (t & 7) * 32;
    for (int i = 0; i < 8; ++i) {
      int d = c0 + i * 4;
      float4 x = *(const float4*)&src[(size_t)row * DIM + d];
      u4x16 tv;
      tv.u[0] = f2bf(x.x); tv.u[1] = f2bf(x.y); tv.u[2] = f2bf(x.z); tv.u[3] = f2bf(x.w);
      *(int2*)&TT[row][d] = tv.v;
    }
    __syncthreads();
    for (int it = 0; it < 4; ++it) {
      int g = t + it * 512;
      int dd = g >> 3, ch = g & 7;
      u8x16 o;
      for (int e = 0; e < 8; ++e) o.u[e] = TT[ch * 8 + e][dd];
      *(int4*)&QbT[((size_t)b * DIM + dd) * QLEN + r0 + ch * 8] = o.v;
    }
  }
}

// ---------------- k_mid (512 thr, grid 768): XCD-chunked heterogeneous overlap.
// Per XCD (bid&7): 2 batches. idx<32 -> qatt2 (16/batch); idx>=32 -> out1 (32/batch).
__global__ __launch_bounds__(512) void k_mid(
    const unsigned short* __restrict__ Et, const unsigned short* __restrict__ PbT,
    const unsigned short* __restrict__ E, const unsigned short* __restrict__ QbT,
    const float* __restrict__ RS2, const float* __restrict__ CL,
    unsigned short* __restrict__ QATTt, float* __restrict__ out1) {
  __shared__ __align__(16) char smem[40960];
  int t = threadIdx.x, lane = t & 63, wid = t >> 6;
  int xcd = blockIdx.x & 7, idx = blockIdx.x >> 3;   // 96 idx per xcd

  if (idx < 32) {
    // ======== qatt2 ========
    int b = 2 * xcd + (idx >> 4);
    int sub = idx & 15;
    int dt = sub >> 2, qt = sub & 3;
    int wm = wid >> 2, wn = wid & 3;
    typedef unsigned short row72[72];
    row72* Wt = (row72*)smem;
    row72* At = (row72*)(smem + 18432);
    float* CSs = (float*)(smem + 36864);
    if (t < 64) {
      int q = qt * 64 + t;
      float L = 0.f;
      for (int tm = 0; tm < 16; ++tm)
        L += CL[((size_t)b * 16 + tm) * QLEN + q];
      CSs[t] = (L > 0.f) ? 1.0f / L : 0.0f;
    }

    int rrow = t >> 3;
    int pch = (t & 7) * 8;
    const unsigned short* Wsrc = Et + ((size_t)b * QLEN + qt * 64 + rrow) * PLEN + pch;
    const unsigned short* Asrc = PbT + ((size_t)b * DIM + dt * 64 + rrow) * PLEN + pch;

    f32x4 acc[2] = {};
    int4 wvv = *(const int4*)Wsrc;
    int4 av = *(const int4*)Asrc;
    __syncthreads();
    float cs = CSs[rrow];

    {
      const unsigned short* wu = (const unsigned short*)&wvv;
      u8x16 wo;
#pragma unroll
      for (int e = 0; e < 8; ++e) wo.u[e] = f2bf(bf2f(wu[e]) * cs);
      *(int4*)&Wt[rrow][pch] = wo.v;
      *(int4*)&At[rrow][pch] = av;
    }
    __syncthreads();
    int cur = 0;
    for (int ps = 0; ps < 16; ++ps) {
      if (ps < 15) {
        int off = (ps + 1) * 64;
        wvv = *(const int4*)(Wsrc + off);
        av = *(const int4*)(Asrc + off);
      }
      for (int kk = 0; kk < 64; kk += 32) {
        short8 bf = *(const short8*)&Wt[cur * 64 + wn * 16 + (lane & 15)][kk + (lane >> 4) * 8];
        for (int i = 0; i < 2; ++i) {
          short8 af = *(const short8*)&At[cur * 64 + wm * 32 + i * 16 + (lane & 15)][kk + (lane >> 4) * 8];
          acc[i] = __builtin_amdgcn_mfma_f32_16x16x32_bf16(af, bf, acc[i], 0, 0, 0);
        }
      }
      if (ps < 15) {
        const unsigned short* wu = (const unsigned short*)&wvv;
        u8x16 wo;
#pragma unroll
        for (int e = 0; e < 8; ++e) wo.u[e] = f2bf(bf2f(wu[e]) * cs);
        int nxt = cur ^ 1;
        *(int4*)&Wt[nxt * 64 + rrow][pch] = wo.v;
        *(int4*)&At[nxt * 64 + rrow][pch] = av;
        cur = nxt;
      }
      __syncthreads();
    }
    int d0 = dt * 64 + wm * 32, q0 = qt * 64 + wn * 16;
    for (int i = 0; i < 2; ++i)
      for (int rr = 0; rr < 4; ++rr) {
        int d = d0 + i * 16 + (lane >> 4) * 4 + rr;
        QATTt[((size_t)b * DIM + d) * QLEN + q0 + (lane & 15)] = f2bf(acc[i][rr]);
      }
  } else {
    // ======== out1 = (1/RS) * E @ QbT^T (64p x 128d) ========
    int u = idx - 32;
    int b = 2 * xcd + (u >> 5);
    int t5 = u & 31;
    int tm = t5 >> 1, tn = t5 & 1;
    const unsigned short* A  = E + ((size_t)b * PLEN + tm * 64) * QLEN;
    const unsigned short* B1 = QbT + ((size_t)b * DIM + tn * 128) * QLEN;
    typedef unsigned short row40k[40];
    row40k* As2 = (row40k*)smem;
    row40k* Bq = (row40k*)(smem + 10240);
    float* invS = (float*)(smem + 30720);
    int wm = wid >> 2, wn = wid & 3;
    if (t < 64) {
      float rs = RS2[((size_t)b * PLEN + tm * 64 + t) * 2]
               + RS2[((size_t)b * PLEN + tm * 64 + t) * 2 + 1];
      invS[t] = (rs > 0.f) ? 1.0f / rs : 0.0f;
    }
    f32x4 acc1[2][2] = {};
    int r = t >> 2, c = (t & 3) * 8;
    int4 rb1 = *(const int4*)&B1[(size_t)r * QLEN + c];
    int4 rav;
    if (t < 256) rav = *(const int4*)&A[(size_t)r * QLEN + c];
    *(int4*)&Bq[r][c] = rb1;
    if (t < 256) *(int4*)&As2[r][c] = rav;
    __syncthreads();
    int cur = 0;
    for (int ki = 0; ki < 8; ++ki) {
      if (ki < 7) {
        int kt = (ki + 1) * 32;
        rb1 = *(const int4*)&B1[(size_t)r * QLEN + kt + c];
        if (t < 256) rav = *(const int4*)&A[(size_t)r * QLEN + kt + c];
      }
      short8 af[2], b1v[2];
      for (int i = 0; i < 2; ++i)
        af[i] = *(const short8*)&As2[cur * 64 + wm * 32 + i * 16 + (lane & 15)][(lane >> 4) * 8];
      for (int j = 0; j < 2; ++j)
        b1v[j] = *(const short8*)&Bq[cur * 128 + wn * 32 + j * 16 + (lane & 15)][(lane >> 4) * 8];
      for (int i = 0; i < 2; ++i)
        for (int j = 0; j < 2; ++j)
          acc1[i][j] = __builtin_amdgcn_mfma_f32_16x16x32_bf16(af[i], b1v[j], acc1[i][j], 0, 0, 0);
      if (ki < 7) {
        int nxt = cur ^ 1;
        *(int4*)&Bq[nxt * 128 + r][c] = rb1;
        if (t < 256) *(int4*)&As2[nxt * 64 + r][c] = rav;
        cur = nxt;
      }
      __syncthreads();
    }
    int d0 = tn * 128 + wn * 32;
    for (int i = 0; i < 2; ++i)
      for (int rr = 0; rr < 4; ++rr) {
        int pl = wm * 32 + i * 16 + (lane >> 4) * 4 + rr;
        float inv = invS[pl];
        int p = tm * 64 + pl;
        size_t rowo = ((size_t)b * PLEN + p) * DIM;
        for (int j = 0; j < 2; ++j) {
          int d = d0 + j * 16 + (lane & 15);
          out1[rowo + d] = acc1[i][j][rr] * inv;
        }
      }
  }
}

// ---------------- k_final2 (512 thr, grid 512, XCD-chunked): out2 = (1/RS)*E @ QATTt^T
__global__ __launch_bounds__(512) void k_final2(
    const unsigned short* __restrict__ E, const unsigned short* __restrict__ QATTt,
    const float* __restrict__ RS2, float* __restrict__ out2) {
  int xcd = blockIdx.x & 7, idx = blockIdx.x >> 3;   // 64 idx per xcd
  int b = 2 * xcd + (idx >> 5);
  int t5 = idx & 31;
  int tm = t5 >> 1, tn = t5 & 1;
  const unsigned short* A  = E + ((size_t)b * PLEN + tm * 64) * QLEN;
  const unsigned short* B2 = QATTt + ((size_t)b * DIM + tn * 128) * QLEN;
  __shared__ __align__(16) unsigned short As[2][64][40];
  __shared__ __align__(16) unsigned short Bc[2][128][40];
  __shared__ float invS[64];
  int t = threadIdx.x, lane = t & 63, wid = t >> 6;
  int wm = wid >> 2, wn = wid & 3;
  if (t < 64) {
    float rs = RS2[((size_t)b * PLEN + tm * 64 + t) * 2]
             + RS2[((size_t)b * PLEN + tm * 64 + t) * 2 + 1];
    invS[t] = (rs > 0.f) ? 1.0f / rs : 0.0f;
  }
  f32x4 acc[2][2] = {};
  int r = t >> 2, c = (t & 3) * 8;
  int4 rb2 = *(const int4*)&B2[(size_t)r * QLEN + c];
  int4 rav;
  if (t < 256) rav = *(const int4*)&A[(size_t)r * QLEN + c];
  *(int4*)&Bc[0][r][c] = rb2;
  if (t < 256) *(int4*)&As[0][r][c] = rav;
  __syncthreads();
  int cur = 0;
  for (int ki = 0; ki < 8; ++ki) {
    if (ki < 7) {
      int kt = (ki + 1) * 32;
      rb2 = *(const int4*)&B2[(size_t)r * QLEN + kt + c];
      if (t < 256) rav = *(const int4*)&A[(size_t)r * QLEN + kt + c];
    }
    short8 af[2], bc[2];
    for (int i = 0; i < 2; ++i)
      af[i] = *(const short8*)&As[cur][wm * 32 + i * 16 + (lane & 15)][(lane >> 4) * 8];
    for (int j = 0; j < 2; ++j)
      bc[j] = *(const short8*)&Bc[cur][wn * 32 + j * 16 + (lane & 15)][(lane >> 4) * 8];
    for (int i = 0; i < 2; ++i)
      for (int j = 0; j < 2; ++j)
        acc[i][j] = __builtin_amdgcn_mfma_f32_16x16x32_bf16(af[i], bc[j], acc[i][j], 0, 0, 0);
    if (ki < 7) {
      int nxt = cur ^ 1;
      *(int4*)&Bc[nxt][r][c] = rb2;
      if (t < 256) *(int4*)&As[nxt][r][c] = rav;
      cur = nxt;
    }
    __syncthreads();
  }
  int d0 = tn * 128 + wn * 32;
  for (int i = 0; i < 2; ++i)
    for (int rr = 0; rr < 4; ++rr) {
      int pl = wm * 32 + i * 16 + (lane >> 4) * 4 + rr;
      float inv = invS[pl];
      int p = tm * 64 + pl;
      size_t rowo = ((size_t)b * PLEN + p) * DIM;
      for (int j = 0; j < 2; ++j) {
        int d = d0 + j * 16 + (lane & 15);
        out2[rowo + d] = acc[i][j][rr] * inv;
      }
    }
}

extern "C" void kernel_launch(void* const* d_in, const int* in_sizes, int n_in,
                              void* d_out, int out_size, void* d_ws, size_t ws_size,
                              hipStream_t stream) {
  const float* passage  = (const float*)d_in[0];
  const float* question = (const float*)d_in[1];
  const int*   pmask    = (const int*)d_in[2];
  const int*   qmask    = (const int*)d_in[3];
  const float* W        = (const float*)d_in[4];
  const float* bias     = (const float*)d_in[5];
  float* out = (float*)d_out;

  const size_t NS = (size_t)NB * PLEN * QLEN;    // 4,194,304
  const size_t NQ = (size_t)NB * QLEN * DIM;     // 1,048,576
  char* w = (char*)d_ws;
  unsigned short* PbT  = (unsigned short*)w; w += NS * 2;
  unsigned short* QbT  = (unsigned short*)w; w += NQ * 2;
  unsigned short* E    = (unsigned short*)w; w += NS * 2;
  unsigned short* Et   = (unsigned short*)w; w += NS * 2;
  unsigned short* QATTt = (unsigned short*)w; w += NQ * 2;
  float* CL  = (float*)w;                    w += (size_t)NB * 16 * QLEN * 4;
  float* RS2 = (float*)w;

  float* out1 = out;
  float* out2 = out + (size_t)NB * PLEN * DIM;

  k_scoreA<<<dim3(512), dim3(512), 0, stream>>>(
      passage, question, W, pmask, qmask, bias, PbT, QbT, CL, RS2, E, Et);
  k_mid<<<dim3(768), dim3(512), 0, stream>>>(
      Et, PbT, E, QbT, RS2, CL, QATTt, out1);
  k_final2<<<dim3(512), dim3(512), 0, stream>>>(
      E, QATTt, RS2, out2);
}